// Round 13
// baseline (339.109 us; speedup 1.0000x reference)
//
#include <hip/hip_runtime.h>

typedef unsigned int u32;
typedef unsigned short u16;
typedef __attribute__((ext_vector_type(8))) _Float16 half8;
typedef __attribute__((ext_vector_type(4))) float f32x4;

#define ROWS  524288   // B*N
#define BROWS 4096     // B
#define EPS   1e-5f

// ---- stats: 64 shards of 1024 floats (atomic chain len 2048/64 = 32); block-coop summing ----
#define S_U   0
#define S_O1  8
#define S_A1  72
#define S_O12 136
#define S_A2  200
#define S_X   264
#define S_X1  328
#define S_X2  392
#define S_X3  456
#define SHARD 1024
#define NSH   64

#define XSTR 40   // LDS row stride in u16: 80 B -> 16-B aligned b128

__device__ __forceinline__ float bl(u32 u){ return __uint_as_float(u << 16); }
__device__ __forceinline__ float bh(u32 u){ return __uint_as_float(u & 0xFFFF0000u); }
__device__ __forceinline__ float b2f(u16 h){ return __uint_as_float(((u32)h) << 16); }
__device__ __forceinline__ u16 f2b(float f){
  u32 u = __float_as_uint(f);
  return (u16)((u + 0x7FFFu + ((u >> 16) & 1u)) >> 16);   // RNE (bf16, output only)
}
__device__ __forceinline__ u16 f2h(float f){ _Float16 h = (_Float16)f; return __builtin_bit_cast(u16, h); }
__device__ __forceinline__ float h2f(u16 x){ return (float)__builtin_bit_cast(_Float16, x); }
__device__ __forceinline__ u32 pack2h(float a, float b){
  auto v = __builtin_amdgcn_cvt_pkrtz(a, b);
  return __builtin_bit_cast(u32, v);
}
__device__ __forceinline__ float lo16(u32 w){ return h2f((u16)(w & 0xFFFF)); }
__device__ __forceinline__ float hi16(u32 w){ return h2f((u16)(w >> 16)); }
__device__ __forceinline__ void unpk4(uint2 v, float* d){
  d[0]=lo16(v.x); d[1]=hi16(v.x); d[2]=lo16(v.y); d[3]=hi16(v.y);
}

__device__ __forceinline__ float tanh_fast(float x){
  float e = __expf(2.0f * x);
  return 1.0f - 2.0f * __builtin_amdgcn_rcpf(e + 1.0f);
}

template<bool F32>
__device__ __forceinline__ float rdp(const void* p, int i){
  if (F32) return ((const float*)p)[i];
  return b2f(((const u16*)p)[i]);
}
template<bool F32>
__device__ __forceinline__ void load_u4(const void* u, int r, float* f){
  if (F32){
    float4 v = ((const float4*)u)[r];
    f[0]=v.x; f[1]=v.y; f[2]=v.z; f[3]=v.w;
  } else {
    uint2 v = ((const uint2*)u)[r];
    f[0]=bl(v.x); f[1]=bh(v.x); f[2]=bl(v.y); f[3]=bh(v.y);
  }
}

// ---------------- dtype detection ----------------
__global__ void k_detect(const u16* __restrict__ u, int* __restrict__ flag){
  int t = threadIdx.x;   // 64
  int bad = 0;
  for (int i = t*4; i < t*4+4; ++i){
    int e = (u[i] >> 7) & 0xFF;
    bad += (e >= 0x90) ? 1 : 0;
  }
#pragma unroll
  for (int off = 32; off >= 1; off >>= 1) bad += __shfl_down(bad, off);
  if (t == 0) *flag = (bad >= 4) ? 1 : 0;
}

// ---------------- stats of u (4 cols) ----------------
template<bool F32>
__device__ __forceinline__ void stats_u_body(const void* __restrict__ u, float* __restrict__ S){
  int tid = blockIdx.x*blockDim.x + threadIdx.x;
  int nt  = gridDim.x*blockDim.x;
  float s[4]={0,0,0,0}, q[4]={0,0,0,0};
  for (int r = tid; r < ROWS; r += nt){
    float f[4]; load_u4<F32>(u, r, f);
#pragma unroll
    for (int k=0;k<4;++k){ s[k]+=f[k]; q[k]+=f[k]*f[k]; }
  }
#pragma unroll
  for (int off=32; off>=1; off>>=1){
#pragma unroll
    for (int k=0;k<4;++k){ s[k]+=__shfl_down(s[k],off); q[k]+=__shfl_down(q[k],off); }
  }
  if ((threadIdx.x & 63) == 0){
    float* Sh = S + (blockIdx.x & (NSH-1))*SHARD;
#pragma unroll
    for (int k=0;k<4;++k){ atomicAdd(&Sh[S_U+k], s[k]); atomicAdd(&Sh[S_U+4+k], q[k]); }
  }
}
__global__ __launch_bounds__(256) void k_stats_u(const void* __restrict__ u, float* __restrict__ S,
                                                 const int* __restrict__ flag){
  if (*flag) stats_u_body<true>(u,S); else stats_u_body<false>(u,S);
}

// ---------------- block preamble: m/rstd of u ----------------
__device__ __forceinline__ void prep_u(const float* __restrict__ S, float* mr, int tid){
  if (tid < 4){
    float s=0.f, q=0.f;
    for (int sh=0; sh<NSH; ++sh){
      s += S[sh*SHARD + S_U + tid];
      q += S[sh*SHARD + S_U + 4 + tid];
    }
    float m = s*(1.0f/ROWS);
    float var = q*(1.0f/ROWS) - m*m;
    mr[tid]   = m;
    mr[4+tid] = rsqrtf(var + EPS);
  }
  __syncthreads();
}
template<bool F32>
__device__ __forceinline__ void bn_u_l(const float* mr, const void* g, const void* b,
                                       const float* f, float* xn){
#pragma unroll
  for (int k=0;k<4;++k)
    xn[k] = (f[k]-mr[k])*(rdp<F32>(g,k)*mr[4+k]) + rdp<F32>(b,k);
}

// ---------------- L1 chain -> f16 LDS row ----------------
template<bool F32>
__device__ __forceinline__ void chain1_to_lds(const float* xn, const void* W1, u16* Xrow){
  u32 buf[16];
#pragma unroll
  for (int jp=0; jp<16; ++jp){
    int j0 = 2*jp, j1 = 2*jp+1;
    float a0 = tanh_fast(xn[0]*rdp<F32>(W1,j0*4+0) + xn[1]*rdp<F32>(W1,j0*4+1)
                       + xn[2]*rdp<F32>(W1,j0*4+2) + xn[3]*rdp<F32>(W1,j0*4+3));
    float a1 = tanh_fast(xn[0]*rdp<F32>(W1,j1*4+0) + xn[1]*rdp<F32>(W1,j1*4+1)
                       + xn[2]*rdp<F32>(W1,j1*4+2) + xn[3]*rdp<F32>(W1,j1*4+3));
    buf[jp] = pack2h(a0, a1);
  }
#pragma unroll
  for (int c=0;c<4;++c){
    uint4 v; v.x = buf[c*4]; v.y = buf[c*4+1]; v.z = buf[c*4+2]; v.w = buf[c*4+3];
    *(uint4*)&Xrow[c*8] = v;
  }
}

// ---------------- in-block BN+Linear folds (64-shard summing) ----------------
template<bool F32>
__device__ __forceinline__ void fold2(const float* __restrict__ S, int offA, int offB,
    const void* gA, const void* bA, const void* WA,
    const void* gB, const void* bB, const void* WB,
    u16* Wt, float* Cb, float* scr /* >=128 floats */)
{
  int tid = threadIdx.x;
  if (tid < 64){
    int L = tid>>5, k = tid&31;
    const void* g = L? gB:gA; const void* b = L? bB:bA;
    int off = L? offB:offA;
    float s=0.f, q=0.f;
    for (int sh=0; sh<NSH; ++sh){
      s += S[sh*SHARD + off + k];
      q += S[sh*SHARD + off + 32 + k];
    }
    float m    = s*(1.0f/ROWS);
    float var  = q*(1.0f/ROWS) - m*m;
    float rstd = rsqrtf(var+EPS);
    float sc = rdp<F32>(g,k)*rstd;
    scr[tid]    = sc;
    scr[64+tid] = rdp<F32>(b,k) - m*sc;
  }
  __syncthreads();
  if (tid < 64){
    int L = tid>>5, j = tid&31;
    const void* W = L? WB:WA;
    float c = 0.f;
#pragma unroll
    for (int k=0;k<32;++k){
      float Wv = rdp<F32>(W, j*32+k);
      Wt[(L*32+j)*XSTR + k] = f2h(Wv * scr[(L<<5)|k]);
      c += Wv * scr[64 + ((L<<5)|k)];
    }
    Cb[L*32+j] = c;
  }
  __syncthreads();
}

template<bool F32>
__device__ __forceinline__ void fold4(const float* __restrict__ S,
    int off0,int off1,int off2,int off3,
    const void* g0,const void* b0,const void* W0,
    const void* g1,const void* b1,const void* W1,
    const void* g2,const void* b2,const void* W2,
    const void* g3,const void* b3,const void* W3,
    u16* Wt, float* Cb, float* scr /* >=256 floats */)
{
  int tid = threadIdx.x;
  __shared__ float scr2[256];
  if (tid < 128){
    int L = tid>>5, k = tid&31;
    const void* g = (L==0)?g0:(L==1)?g1:(L==2)?g2:g3;
    const void* b = (L==0)?b0:(L==1)?b1:(L==2)?b2:b3;
    int off = (L==0)?off0:(L==1)?off1:(L==2)?off2:off3;
    float s=0.f, q=0.f;
    for (int sh=0; sh<NSH; ++sh){
      s += S[sh*SHARD + off + k];
      q += S[sh*SHARD + off + 32 + k];
    }
    float m    = s*(1.0f/ROWS);
    float var  = q*(1.0f/ROWS) - m*m;
    float rstd = rsqrtf(var+EPS);
    float sc = rdp<F32>(g,k)*rstd;
    scr[tid]  = sc;
    scr2[tid] = rdp<F32>(b,k) - m*sc;
  }
  __syncthreads();
  if (tid < 128){
    int L = tid>>5, j = tid&31;
    const void* W = (L==0)?W0:(L==1)?W1:(L==2)?W2:W3;
    float c = 0.f;
#pragma unroll
    for (int k=0;k<32;++k){
      float Wv = rdp<F32>(W, j*32+k);
      Wt[(L*32+j)*XSTR + k] = f2h(Wv * scr[(L<<5)|k]);
      c += Wv * scr2[(L<<5)|k];
    }
    Cb[L*32+j] = c;
  }
  __syncthreads();
}

// ---------------- MFMA layer: Y^T = W.X^T (C: col=sample, row=feature) ----------------
#define KIND_TANH          0
#define KIND_TANHRES       2
#define KIND_TANHRES_ATREG 3
template<int KIND>
__device__ __forceinline__ void mfma_layer(u16* X, const u16* Wt, const float* Cb,
                                           int L, int wv, int lane, const u32* at_pk)
{
  int ln15 = lane & 15, quad = lane >> 4;
  half8 w0 = *(const half8*)&Wt[(L*32 + ln15     )*XSTR + quad*8];
  half8 w1 = *(const half8*)&Wt[(L*32 + ln15 + 16)*XSTR + quad*8];
  float bias0[4], bias1[4];
#pragma unroll
  for (int reg=0;reg<4;++reg){
    bias0[reg] = Cb[L*32 +      quad*4 + reg];
    bias1[reg] = Cb[L*32 + 16 + quad*4 + reg];
  }
  int rowbase = wv*64;
#pragma unroll
  for (int Mt=0; Mt<4; ++Mt){
    int s = rowbase + Mt*16 + ln15;
    half8 bfr = *(const half8*)&X[s*XSTR + quad*8];
    f32x4 c0 = {0.f,0.f,0.f,0.f}, c1 = {0.f,0.f,0.f,0.f};
    c0 = __builtin_amdgcn_mfma_f32_16x16x32_f16(w0, bfr, c0, 0,0,0);
    c1 = __builtin_amdgcn_mfma_f32_16x16x32_f16(w1, bfr, c1, 0,0,0);
    float o0[4], o1v[4];
    if (KIND == KIND_TANHRES || KIND == KIND_TANHRES_ATREG){
      unpk4(*(const uint2*)&X[s*XSTR +      quad*4], o0);
      unpk4(*(const uint2*)&X[s*XSTR + 16 + quad*4], o1v);
    }
    float a0v[4], a1v[4];
    if (KIND == KIND_TANHRES_ATREG){
      a0v[0]=lo16(at_pk[Mt*4+0]); a0v[1]=hi16(at_pk[Mt*4+0]);
      a0v[2]=lo16(at_pk[Mt*4+1]); a0v[3]=hi16(at_pk[Mt*4+1]);
      a1v[0]=lo16(at_pk[Mt*4+2]); a1v[1]=hi16(at_pk[Mt*4+2]);
      a1v[2]=lo16(at_pk[Mt*4+3]); a1v[3]=hi16(at_pk[Mt*4+3]);
    }
    float v0[4], v1[4];
#pragma unroll
    for (int reg=0;reg<4;++reg){
      float a = c0[reg] + bias0[reg];
      float b = c1[reg] + bias1[reg];
      if (KIND == KIND_TANH){ a = tanh_fast(a); b = tanh_fast(b); }
      else if (KIND == KIND_TANHRES){ a = o0[reg] + tanh_fast(a); b = o1v[reg] + tanh_fast(b); }
      else if (KIND == KIND_TANHRES_ATREG){
        a = (o0[reg] + tanh_fast(a)) * a0v[reg];
        b = (o1v[reg] + tanh_fast(b)) * a1v[reg];
      }
      v0[reg] = a; v1[reg] = b;
    }
    uint2 w0o, w1o;
    w0o.x = pack2h(v0[0], v0[1]); w0o.y = pack2h(v0[2], v0[3]);
    w1o.x = pack2h(v1[0], v1[1]); w1o.y = pack2h(v1[2], v1[3]);
    *(uint2*)&X[s*XSTR +      quad*4] = w0o;
    *(uint2*)&X[s*XSTR + 16 + quad*4] = w1o;
  }
}

// ---------------- MFMA logits + in-register softmax (cross-quad shfl) -> at_pk ----------------
__device__ __forceinline__ void mfma_logits_softmax(const u16* X, const u16* Wt, const float* Cb,
    int L, int wv, int lane, const int* __restrict__ mask, int maskbase, u32* at_pk)
{
  int ln15 = lane & 15, quad = lane >> 4;
  half8 w0 = *(const half8*)&Wt[(L*32 + ln15     )*XSTR + quad*8];
  half8 w1 = *(const half8*)&Wt[(L*32 + ln15 + 16)*XSTR + quad*8];
  float bias0[4], bias1[4];
#pragma unroll
  for (int reg=0;reg<4;++reg){
    bias0[reg] = Cb[L*32 +      quad*4 + reg];
    bias1[reg] = Cb[L*32 + 16 + quad*4 + reg];
  }
  int rowbase = wv*64;
#pragma unroll
  for (int Mt=0; Mt<4; ++Mt){
    int s = rowbase + Mt*16 + ln15;
    half8 bfr = *(const half8*)&X[s*XSTR + quad*8];
    f32x4 c0 = {0.f,0.f,0.f,0.f}, c1 = {0.f,0.f,0.f,0.f};
    c0 = __builtin_amdgcn_mfma_f32_16x16x32_f16(w0, bfr, c0, 0,0,0);
    c1 = __builtin_amdgcn_mfma_f32_16x16x32_f16(w1, bfr, c1, 0,0,0);
    float l0[4], l1[4];
#pragma unroll
    for (int reg=0;reg<4;++reg){ l0[reg] = c0[reg]+bias0[reg]; l1[reg] = c1[reg]+bias1[reg]; }
    float mx = l0[0];
#pragma unroll
    for (int reg=1;reg<4;++reg) mx = fmaxf(mx, l0[reg]);
#pragma unroll
    for (int reg=0;reg<4;++reg) mx = fmaxf(mx, l1[reg]);
    mx = fmaxf(mx, __shfl_xor(mx, 16));
    mx = fmaxf(mx, __shfl_xor(mx, 32));
    float sum = 0.f;
#pragma unroll
    for (int reg=0;reg<4;++reg){ l0[reg] = __expf(l0[reg]-mx); sum += l0[reg]; }
#pragma unroll
    for (int reg=0;reg<4;++reg){ l1[reg] = __expf(l1[reg]-mx); sum += l1[reg]; }
    sum += __shfl_xor(sum, 16);
    sum += __shfl_xor(sum, 32);
    float inv = __builtin_amdgcn_rcpf(sum);
    bool mz = (mask[maskbase + Mt*16 + ln15] == 0);
#pragma unroll
    for (int reg=0;reg<4;++reg){
      l0[reg] *= inv; l1[reg] *= inv;
      if (mz){ l0[reg] = -__builtin_inff(); l1[reg] = -__builtin_inff(); }
    }
    at_pk[Mt*4+0] = pack2h(l0[0], l0[1]);
    at_pk[Mt*4+1] = pack2h(l0[2], l0[3]);
    at_pk[Mt*4+2] = pack2h(l1[0], l1[1]);
    at_pk[Mt*4+3] = pack2h(l1[2], l1[3]);
  }
}

// ---------------- column stats reducers (64-sharded atomics) ----------------
__device__ __forceinline__ void reduce_f16(const u16* X, float* lds2,
                                           float* __restrict__ S, int offS, int shard)
{
  int tid = threadIdx.x;
  __syncthreads();
  {
    int j = tid & 31, seg = tid >> 5;
    float s=0.f, q=0.f;
    for (int q2=0;q2<32;++q2){
      float v = h2f(X[(seg*32+q2)*XSTR + j]);
      s += v; q = fmaf(v,v,q);
    }
    lds2[seg*32+j] = s;
    lds2[256 + seg*32+j] = q;
  }
  __syncthreads();
  if (tid < 64){
    int j = tid & 31; bool isq = tid >= 32;
    const float* src = lds2 + (isq?256:0);
    float tot=0.f;
#pragma unroll
    for (int sg=0;sg<8;++sg) tot += src[sg*32+j];
    atomicAdd(&S[shard*SHARD + offS + (isq?32:0) + j], tot);
  }
  __syncthreads();
}

__device__ __forceinline__ void reduce_f32(const float* Xs, float* lds2,
                                           float* __restrict__ S, int offS, int shard)
{
  int tid = threadIdx.x;
  __syncthreads();
  {
    int j = tid & 31, seg = tid >> 5;
    float s=0.f, q=0.f;
    for (int q2=0;q2<32;++q2){
      float v = Xs[(seg*32+q2)*33 + j];
      s += v; q = fmaf(v,v,q);
    }
    lds2[seg*32+j] = s;
    lds2[256 + seg*32+j] = q;
  }
  __syncthreads();
  if (tid < 64){
    int j = tid & 31; bool isq = tid >= 32;
    const float* src = lds2 + (isq?256:0);
    float tot=0.f;
#pragma unroll
    for (int sg=0;sg<8;++sg) tot += src[sg*32+j];
    atomicAdd(&S[shard*SHARD + offS + (isq?32:0) + j], tot);
  }
  __syncthreads();
}

// ---------------- pass1: stats of o1, a1 (recompute, no materialize) ----------------
template<bool F32>
__device__ __forceinline__ void pass1_body(const void* __restrict__ u,
    const void* pg1, const void* pb1, const void* pw1,
    const void* og1, const void* ob1, const void* ow1,
    float* __restrict__ S, float* Xs, float* lds2, float* mr)
{
  int tid = threadIdx.x;
  int r = blockIdx.x*256 + tid;
  int shard = blockIdx.x & (NSH-1);
  prep_u(S, mr, tid);
  float f[4]; load_u4<F32>(u,r,f);
  float xn[4];
  float* Xp = Xs + tid*33;

  bn_u_l<F32>(mr, pg1, pb1, f, xn);
#pragma unroll
  for (int j=0;j<32;++j)
    Xp[j] = tanh_fast(xn[0]*rdp<F32>(pw1,j*4+0) + xn[1]*rdp<F32>(pw1,j*4+1)
                    + xn[2]*rdp<F32>(pw1,j*4+2) + xn[3]*rdp<F32>(pw1,j*4+3));
  reduce_f32(Xs, lds2, S, S_O1, shard);

  bn_u_l<F32>(mr, og1, ob1, f, xn);
#pragma unroll
  for (int j=0;j<32;++j)
    Xp[j] = tanh_fast(xn[0]*rdp<F32>(ow1,j*4+0) + xn[1]*rdp<F32>(ow1,j*4+1)
                    + xn[2]*rdp<F32>(ow1,j*4+2) + xn[3]*rdp<F32>(ow1,j*4+3));
  reduce_f32(Xs, lds2, S, S_A1, shard);
}
__global__ __launch_bounds__(256) void k_pass1(const void* __restrict__ u,
    const void* pg1, const void* pb1, const void* pw1,
    const void* og1, const void* ob1, const void* ow1,
    float* __restrict__ S, const int* __restrict__ flag){
  __shared__ float Xs[256*33];
  __shared__ float lds2[512];
  __shared__ float mr[8];
  if (*flag) pass1_body<true >(u,pg1,pb1,pw1,og1,ob1,ow1,S,Xs,lds2,mr);
  else       pass1_body<false>(u,pg1,pb1,pw1,og1,ob1,ow1,S,Xs,lds2,mr);
}

// ---------------- pass2: stats of o12, a2 (recompute chains + MFMA) ----------------
template<bool F32>
__device__ __forceinline__ void pass2_body(const void* __restrict__ u,
    const void* pg1, const void* pb1, const void* pw1,
    const void* og1, const void* ob1, const void* ow1,
    const void* pg2, const void* pb2, const void* pw2,
    const void* og2, const void* ob2, const void* ow2,
    float* __restrict__ S, u16* X, u16* Wt, float* Cb, float* lds2, float* mr)
{
  int tid = threadIdx.x;
  int wv = tid >> 6, lane = tid & 63;
  int r = blockIdx.x*256 + tid;
  int shard = blockIdx.x & (NSH-1);
  prep_u(S, mr, tid);
  fold2<F32>(S, S_O1, S_A1, pg2,pb2,pw2, og2,ob2,ow2, Wt, Cb, lds2);

  float f[4], xn[4];
  load_u4<F32>(u,r,f);

  bn_u_l<F32>(mr, pg1, pb1, f, xn);
  chain1_to_lds<F32>(xn, pw1, X + tid*XSTR);              // o1
  mfma_layer<KIND_TANHRES>(X, Wt, Cb, 0, wv, lane, 0);    // o12
  reduce_f16(X, lds2, S, S_O12, shard);

  bn_u_l<F32>(mr, og1, ob1, f, xn);
  chain1_to_lds<F32>(xn, ow1, X + tid*XSTR);              // a1
  mfma_layer<KIND_TANH  >(X, Wt, Cb, 1, wv, lane, 0);     // a2
  reduce_f16(X, lds2, S, S_A2, shard);
}
__global__ __launch_bounds__(256) void k_pass2(const void* __restrict__ u,
    const void* pg1, const void* pb1, const void* pw1,
    const void* og1, const void* ob1, const void* ow1,
    const void* pg2, const void* pb2, const void* pw2,
    const void* og2, const void* ob2, const void* ow2,
    float* __restrict__ S, const int* __restrict__ flag){
  __shared__ u16 X[256*XSTR];      // 20480 B
  __shared__ u16 Wt[2*32*XSTR];    //  5120 B
  __shared__ float Cb[64];
  __shared__ float lds2[512];
  __shared__ float mr[8];
  if (*flag) pass2_body<true >(u,pg1,pb1,pw1,og1,ob1,ow1,pg2,pb2,pw2,og2,ob2,ow2,S,X,Wt,Cb,lds2,mr);
  else       pass2_body<false>(u,pg1,pb1,pw1,og1,ob1,ow1,pg2,pb2,pw2,og2,ob2,ow2,S,X,Wt,Cb,lds2,mr);
}

// ---------------- pass3: full chain + reg-softmax + pooling + fused S_X ----------------
template<bool F32>
__device__ __forceinline__ void pass3_body(const void* __restrict__ u, const int* __restrict__ mask,
    const void* pg1, const void* pb1, const void* pw1,
    const void* og1, const void* ob1, const void* ow1,
    const void* pg2, const void* pb2, const void* pw2,
    const void* og2, const void* ob2, const void* ow2,
    const void* pg3, const void* pb3, const void* pw3,
    const void* og3, const void* ob3, const void* ow3,
    float* __restrict__ x, float* __restrict__ S,
    u16* X, u16* Wt, float* Cb, float* red2, float* mr)
{
  int tid = threadIdx.x;
  int wv = tid >> 6, lane = tid & 63;
  int r = blockIdx.x*256 + tid;
  prep_u(S, mr, tid);
  // L0=2O(S_A1), L1=3O(S_A2), L2=2P(S_O1), L3=3P(S_O12)
  fold4<F32>(S, S_A1, S_A2, S_O1, S_O12,
             og2,ob2,ow2, og3,ob3,ow3, pg2,pb2,pw2, pg3,pb3,pw3,
             Wt, Cb, red2);

  float f[4], xn[4];
  load_u4<F32>(u,r,f);
  u32 at_pk[16];
  int maskbase = blockIdx.x*256 + wv*64;

  // ---- omega ----
  bn_u_l<F32>(mr, og1, ob1, f, xn);
  chain1_to_lds<F32>(xn, ow1, X + tid*XSTR);                   // a1
  mfma_layer<KIND_TANH>(X, Wt, Cb, 0, wv, lane, 0);            // a2
  mfma_logits_softmax(X, Wt, Cb, 1, wv, lane, mask, maskbase, at_pk);

  // ---- phi ----
  bn_u_l<F32>(mr, pg1, pb1, f, xn);
  chain1_to_lds<F32>(xn, pw1, X + tid*XSTR);                   // o1
  mfma_layer<KIND_TANHRES   >(X, Wt, Cb, 2, wv, lane, 0);      // o12
  mfma_layer<KIND_TANHRES_ATREG>(X, Wt, Cb, 3, wv, lane, at_pk); // xm*at

  // ---- pool over 128 neighbors (2 groups per block) + fused S_X ----
  __syncthreads();
  {
    int jj = tid & 31, cgrp = (tid >> 5) & 3, half = tid >> 7;
    float s2 = 0.f;
    for (int q2=0;q2<32;++q2) s2 += h2f(X[(half*128 + cgrp*32 + q2)*XSTR + jj]);
    red2[tid] = s2;
  }
  __syncthreads();
  if (tid < 64){
    int half = tid >> 5, j = tid & 31;
    float v = red2[half*128+j] + red2[half*128+32+j] + red2[half*128+64+j] + red2[half*128+96+j];
    x[(blockIdx.x*2 + half)*32 + j] = v;
    float* Sh = S + (blockIdx.x & (NSH-1))*SHARD;
    atomicAdd(&Sh[S_X+j], v);
    atomicAdd(&Sh[S_X+32+j], v*v);
  }
}
__global__ __launch_bounds__(256) void k_pass3(const void* __restrict__ u, const int* __restrict__ mask,
    const void* pg1, const void* pb1, const void* pw1,
    const void* og1, const void* ob1, const void* ow1,
    const void* pg2, const void* pb2, const void* pw2,
    const void* og2, const void* ob2, const void* ow2,
    const void* pg3, const void* pb3, const void* pw3,
    const void* og3, const void* ob3, const void* ow3,
    float* __restrict__ x, float* __restrict__ S, const int* __restrict__ flag){
  __shared__ u16 X [256*XSTR];   // 20480 B
  __shared__ u16 Wt[4*32*XSTR];  // 10240 B
  __shared__ float Cb[128];
  __shared__ float red2[256];
  __shared__ float mr[8];
  if (*flag) pass3_body<true >(u,mask,pg1,pb1,pw1,og1,ob1,ow1,pg2,pb2,pw2,og2,ob2,ow2,
                               pg3,pb3,pw3,og3,ob3,ow3,x,S,X,Wt,Cb,red2,mr);
  else       pass3_body<false>(u,mask,pg1,pb1,pw1,og1,ob1,ow1,pg2,pb2,pw2,og2,ob2,ow2,
                               pg3,pb3,pw3,og3,ob3,ow3,x,S,X,Wt,Cb,red2,mr);
}

// ---------------- theta layer (preamble stats, two-stage reduce) ----------------
template<bool F32>
__device__ __forceinline__ void theta_body(const float* __restrict__ X, float* __restrict__ S, int offin,
    const void* g, const void* bt, const void* W, float* __restrict__ Y, int offout,
    float* lds, float* lds2)
{
  int r = blockIdx.x*blockDim.x + threadIdx.x;   // 4096 rows exactly
  int tid = threadIdx.x;
  int shard = blockIdx.x & (NSH-1);
  if (tid < 32){
    float s=0.f, q=0.f;
    for (int sh=0; sh<NSH; ++sh){
      s += S[sh*SHARD + offin + tid];
      q += S[sh*SHARD + offin + 32 + tid];
    }
    float m = s*(1.0f/BROWS);
    float var = q*(1.0f/BROWS) - m*m;
    lds2[tid]    = m;
    lds2[32+tid] = rsqrtf(var + EPS);
  }
  __syncthreads();
  float* Xp = lds + tid*33;
#pragma unroll
  for (int k=0;k<32;++k){
    Xp[k] = (X[(size_t)r*32+k] - lds2[k]) * (rdp<F32>(g,k)*lds2[32+k]) + rdp<F32>(bt,k);
  }
  float out[32];
#pragma unroll
  for (int j=0;j<32;++j){
    float acc = 0.f;
#pragma unroll
    for (int k=0;k<32;++k) acc = fmaf(rdp<F32>(W, j*32+k), Xp[k], acc);
    out[j] = tanh_fast(acc);
    Y[(size_t)r*32+j] = out[j];
  }
  __syncthreads();
#pragma unroll
  for (int j=0;j<32;++j) Xp[j] = out[j];
  reduce_f32(lds, lds2, S, offout, shard);
}
__global__ __launch_bounds__(256) void k_theta(const float* X, float* S, int offin,
    const void* g, const void* bt, const void* W, float* Y, int offout, const int* __restrict__ flag){
  __shared__ float lds[256*33];
  __shared__ float lds2[512];
  if (*flag) theta_body<true >(X,S,offin,g,bt,W,Y,offout,lds,lds2);
  else       theta_body<false>(X,S,offin,g,bt,W,Y,offout,lds,lds2);
}

// ---------------- final layer ----------------
template<bool F32>
__device__ __forceinline__ void theta4_body(const float* __restrict__ X, const float* __restrict__ S, int offin,
    const void* g, const void* bt, const void* w4, const void* b4, void* out, float* ms)
{
  int r = blockIdx.x*blockDim.x + threadIdx.x;
  int tid = threadIdx.x;
  if (tid < 32){
    float s=0.f, q=0.f;
    for (int sh=0; sh<NSH; ++sh){
      s += S[sh*SHARD + offin + tid];
      q += S[sh*SHARD + offin + 32 + tid];
    }
    float m = s*(1.0f/BROWS);
    float var = q*(1.0f/BROWS) - m*m;
    ms[tid]    = m;
    ms[32+tid] = rsqrtf(var + EPS);
  }
  __syncthreads();
  float acc = rdp<F32>(b4, 0);
#pragma unroll
  for (int k=0;k<32;++k){
    float xnv = (X[(size_t)r*32+k] - ms[k]) * (rdp<F32>(g,k)*ms[32+k]) + rdp<F32>(bt,k);
    acc = fmaf(rdp<F32>(w4,k), xnv, acc);
  }
  if (F32) ((float*)out)[r] = acc;
  else     ((u16*)out)[r]  = f2b(acc);
}
__global__ __launch_bounds__(256) void k_theta4(const float* X, const float* S, int offin,
    const void* g, const void* bt, const void* w4, const void* b4, void* out, const int* __restrict__ flag){
  __shared__ float ms[64];
  if (*flag) theta4_body<true >(X,S,offin,g,bt,w4,b4,out,ms);
  else       theta4_body<false>(X,S,offin,g,bt,w4,b4,out,ms);
}

extern "C" void kernel_launch(void* const* d_in, const int* in_sizes, int n_in,
                              void* d_out, int out_size, void* d_ws, size_t ws_size,
                              hipStream_t stream)
{
  const void* u    = d_in[0];
  const int*  mask = (const int*)d_in[1];
  const void *pg1=d_in[2],  *pb1=d_in[3],  *pw1=d_in[4];
  const void *pg2=d_in[5],  *pb2=d_in[6],  *pw2=d_in[7];
  const void *pg3=d_in[8],  *pb3=d_in[9],  *pw3=d_in[10];
  const void *og1=d_in[11], *ob1=d_in[12], *ow1=d_in[13];
  const void *og2=d_in[14], *ob2=d_in[15], *ow2=d_in[16];
  const void *og3=d_in[17], *ob3=d_in[18], *ow3=d_in[19];
  const void *tg1=d_in[20], *tb1=d_in[21], *tw1=d_in[22];
  const void *tg2=d_in[23], *tb2=d_in[24], *tw2=d_in[25];
  const void *tg3=d_in[26], *tb3=d_in[27], *tw3=d_in[28];
  const void *tg4=d_in[29], *tb4=d_in[30], *tw4=d_in[31], *tbb4=d_in[32];

  char* ws = (char*)d_ws;
  int*   flag = (int*)ws;                    // byte 0
  float* S    = (float*)(ws + 4096);         // 64 shards x 1024 floats = 256 KB
  float* x    = (float*)(ws + 524288);       // 4096*32 f32 x4
  float* x1 = x  + BROWS*32;
  float* x2 = x1 + BROWS*32;
  float* x3 = x2 + BROWS*32;

  (void)hipMemsetAsync(ws, 0, 4096 + NSH*SHARD*4, stream);  // zero flag + sharded stats
  k_detect<<<1, 64, 0, stream>>>((const u16*)u, flag);
  k_stats_u<<<1024, 256, 0, stream>>>(u, S, flag);
  k_pass1<<<2048, 256, 0, stream>>>(u, pg1,pb1,pw1, og1,ob1,ow1, S, flag);
  k_pass2<<<2048, 256, 0, stream>>>(u, pg1,pb1,pw1, og1,ob1,ow1,
                                    pg2,pb2,pw2, og2,ob2,ow2, S, flag);
  k_pass3<<<2048, 256, 0, stream>>>(u, mask, pg1,pb1,pw1, og1,ob1,ow1,
                                    pg2,pb2,pw2, og2,ob2,ow2,
                                    pg3,pb3,pw3, og3,ob3,ow3, x, S, flag);
  k_theta<<<16, 256, 0, stream>>>(x,  S, S_X,  tg1,tb1,tw1, x1, S_X1, flag);
  k_theta<<<16, 256, 0, stream>>>(x1, S, S_X1, tg2,tb2,tw2, x2, S_X2, flag);
  k_theta<<<16, 256, 0, stream>>>(x2, S, S_X2, tg3,tb3,tw3, x3, S_X3, flag);
  k_theta4<<<16, 256, 0, stream>>>(x3, S, S_X3, tg4,tb4,tw4,tbb4, d_out, flag);
}

// Round 14
// 331.646 us; speedup vs baseline: 1.0225x; 1.0225x over previous
//
#include <hip/hip_runtime.h>

typedef unsigned int u32;
typedef unsigned short u16;
typedef __attribute__((ext_vector_type(8))) _Float16 half8;
typedef __attribute__((ext_vector_type(4))) float f32x4;

#define ROWS  524288   // B*N
#define BROWS 4096     // B
#define EPS   1e-5f

// ---- stats: 64 shards of 1024 floats; block-coop summing ----
#define S_U   0
#define S_O1  8
#define S_A1  72
#define S_O12 136
#define S_A2  200
#define S_X   264
#define S_X1  328
#define S_X2  392
#define S_X3  456
#define SHARD 1024
#define NSH   64

#define XSTR 40   // LDS row stride in u16

__device__ __forceinline__ float bl(u32 u){ return __uint_as_float(u << 16); }
__device__ __forceinline__ float bh(u32 u){ return __uint_as_float(u & 0xFFFF0000u); }
__device__ __forceinline__ float b2f(u16 h){ return __uint_as_float(((u32)h) << 16); }
__device__ __forceinline__ u16 f2b(float f){
  u32 u = __float_as_uint(f);
  return (u16)((u + 0x7FFFu + ((u >> 16) & 1u)) >> 16);   // RNE (bf16, output only)
}
__device__ __forceinline__ u16 f2h(float f){ _Float16 h = (_Float16)f; return __builtin_bit_cast(u16, h); }
__device__ __forceinline__ float h2f(u16 x){ return (float)__builtin_bit_cast(_Float16, x); }
__device__ __forceinline__ u32 pack2h(float a, float b){
  auto v = __builtin_amdgcn_cvt_pkrtz(a, b);
  return __builtin_bit_cast(u32, v);
}
__device__ __forceinline__ float lo16(u32 w){ return h2f((u16)(w & 0xFFFF)); }
__device__ __forceinline__ float hi16(u32 w){ return h2f((u16)(w >> 16)); }
__device__ __forceinline__ void unpk4(uint2 v, float* d){
  d[0]=lo16(v.x); d[1]=hi16(v.x); d[2]=lo16(v.y); d[3]=hi16(v.y);
}

// Padé(5,4) tanh: no v_exp; err <= ~1e-3, clamped to [-1,1].
__device__ __forceinline__ float tanh_fast(float x){
  float x2 = x*x;
  float num = fmaf(x2 + 105.0f, x2, 945.0f) * x;
  float den = fmaf(fmaf(x2, 15.0f, 420.0f), x2, 945.0f);
  float v = num * __builtin_amdgcn_rcpf(den);
  return fminf(1.0f, fmaxf(-1.0f, v));
}

template<bool F32>
__device__ __forceinline__ float rdp(const void* p, int i){
  if (F32) return ((const float*)p)[i];
  return b2f(((const u16*)p)[i]);
}
template<bool F32>
__device__ __forceinline__ void load_u4(const void* u, int r, float* f){
  if (F32){
    float4 v = ((const float4*)u)[r];
    f[0]=v.x; f[1]=v.y; f[2]=v.z; f[3]=v.w;
  } else {
    uint2 v = ((const uint2*)u)[r];
    f[0]=bl(v.x); f[1]=bh(v.x); f[2]=bl(v.y); f[3]=bh(v.y);
  }
}

// ---- LDS row <-> global f16 tensor ----
__device__ __forceinline__ void g2lrow(const u16* __restrict__ g, int r, u16* X, int tid){
  const uint4* src = (const uint4*)&g[(size_t)r*32];
  uint4* dst = (uint4*)&X[tid*XSTR];
#pragma unroll
  for (int c=0;c<4;++c) dst[c] = src[c];
}
__device__ __forceinline__ void l2grow(const u16* X, int tid, u16* __restrict__ g, int r){
  const uint4* src = (const uint4*)&X[tid*XSTR];
  uint4* dst = (uint4*)&g[(size_t)r*32];
#pragma unroll
  for (int c=0;c<4;++c) dst[c] = src[c];
}

// ---------------- dtype detection ----------------
__global__ void k_detect(const u16* __restrict__ u, int* __restrict__ flag){
  int t = threadIdx.x;   // 64
  int bad = 0;
  for (int i = t*4; i < t*4+4; ++i){
    int e = (u[i] >> 7) & 0xFF;
    bad += (e >= 0x90) ? 1 : 0;
  }
#pragma unroll
  for (int off = 32; off >= 1; off >>= 1) bad += __shfl_down(bad, off);
  if (t == 0) *flag = (bad >= 4) ? 1 : 0;
}

// ---------------- stats of u (4 cols) ----------------
template<bool F32>
__device__ __forceinline__ void stats_u_body(const void* __restrict__ u, float* __restrict__ S){
  int tid = blockIdx.x*blockDim.x + threadIdx.x;
  int nt  = gridDim.x*blockDim.x;
  float s[4]={0,0,0,0}, q[4]={0,0,0,0};
  for (int r = tid; r < ROWS; r += nt){
    float f[4]; load_u4<F32>(u, r, f);
#pragma unroll
    for (int k=0;k<4;++k){ s[k]+=f[k]; q[k]+=f[k]*f[k]; }
  }
#pragma unroll
  for (int off=32; off>=1; off>>=1){
#pragma unroll
    for (int k=0;k<4;++k){ s[k]+=__shfl_down(s[k],off); q[k]+=__shfl_down(q[k],off); }
  }
  if ((threadIdx.x & 63) == 0){
    float* Sh = S + (blockIdx.x & (NSH-1))*SHARD;
#pragma unroll
    for (int k=0;k<4;++k){ atomicAdd(&Sh[S_U+k], s[k]); atomicAdd(&Sh[S_U+4+k], q[k]); }
  }
}
__global__ __launch_bounds__(256) void k_stats_u(const void* __restrict__ u, float* __restrict__ S,
                                                 const int* __restrict__ flag){
  if (*flag) stats_u_body<true>(u,S); else stats_u_body<false>(u,S);
}

// ---------------- block preamble: m/rstd of u ----------------
__device__ __forceinline__ void prep_u(const float* __restrict__ S, float* mr, int tid){
  if (tid < 4){
    float s=0.f, q=0.f;
    for (int sh=0; sh<NSH; ++sh){
      s += S[sh*SHARD + S_U + tid];
      q += S[sh*SHARD + S_U + 4 + tid];
    }
    float m = s*(1.0f/ROWS);
    float var = q*(1.0f/ROWS) - m*m;
    mr[tid]   = m;
    mr[4+tid] = rsqrtf(var + EPS);
  }
  __syncthreads();
}
template<bool F32>
__device__ __forceinline__ void bn_u_l(const float* mr, const void* g, const void* b,
                                       const float* f, float* xn){
#pragma unroll
  for (int k=0;k<4;++k)
    xn[k] = (f[k]-mr[k])*(rdp<F32>(g,k)*mr[4+k]) + rdp<F32>(b,k);
}

// ---------------- L1 chain -> f16 LDS row ----------------
template<bool F32>
__device__ __forceinline__ void chain1_to_lds(const float* xn, const void* W1, u16* Xrow){
  u32 buf[16];
#pragma unroll
  for (int jp=0; jp<16; ++jp){
    int j0 = 2*jp, j1 = 2*jp+1;
    float a0 = tanh_fast(xn[0]*rdp<F32>(W1,j0*4+0) + xn[1]*rdp<F32>(W1,j0*4+1)
                       + xn[2]*rdp<F32>(W1,j0*4+2) + xn[3]*rdp<F32>(W1,j0*4+3));
    float a1 = tanh_fast(xn[0]*rdp<F32>(W1,j1*4+0) + xn[1]*rdp<F32>(W1,j1*4+1)
                       + xn[2]*rdp<F32>(W1,j1*4+2) + xn[3]*rdp<F32>(W1,j1*4+3));
    buf[jp] = pack2h(a0, a1);
  }
#pragma unroll
  for (int c=0;c<4;++c){
    uint4 v; v.x = buf[c*4]; v.y = buf[c*4+1]; v.z = buf[c*4+2]; v.w = buf[c*4+3];
    *(uint4*)&Xrow[c*8] = v;
  }
}

// ---------------- in-block BN+Linear folds (64-shard summing) ----------------
template<bool F32>
__device__ __forceinline__ void fold2(const float* __restrict__ S, int offA, int offB,
    const void* gA, const void* bA, const void* WA,
    const void* gB, const void* bB, const void* WB,
    u16* Wt, float* Cb, float* scr /* >=128 floats */)
{
  int tid = threadIdx.x;
  if (tid < 64){
    int L = tid>>5, k = tid&31;
    const void* g = L? gB:gA; const void* b = L? bB:bA;
    int off = L? offB:offA;
    float s=0.f, q=0.f;
    for (int sh=0; sh<NSH; ++sh){
      s += S[sh*SHARD + off + k];
      q += S[sh*SHARD + off + 32 + k];
    }
    float m    = s*(1.0f/ROWS);
    float var  = q*(1.0f/ROWS) - m*m;
    float rstd = rsqrtf(var+EPS);
    float sc = rdp<F32>(g,k)*rstd;
    scr[tid]    = sc;
    scr[64+tid] = rdp<F32>(b,k) - m*sc;
  }
  __syncthreads();
  if (tid < 64){
    int L = tid>>5, j = tid&31;
    const void* W = L? WB:WA;
    float c = 0.f;
#pragma unroll
    for (int k=0;k<32;++k){
      float Wv = rdp<F32>(W, j*32+k);
      Wt[(L*32+j)*XSTR + k] = f2h(Wv * scr[(L<<5)|k]);
      c += Wv * scr[64 + ((L<<5)|k)];
    }
    Cb[L*32+j] = c;
  }
  __syncthreads();
}

// ---------------- MFMA layer: Y^T = W.X^T ----------------
#define KIND_TANH          0
#define KIND_TANHRES       2
#define KIND_TANHRES_ATREG 3
template<int KIND>
__device__ __forceinline__ void mfma_layer(u16* X, const u16* Wt, const float* Cb,
                                           int L, int wv, int lane, const u32* at_pk)
{
  int ln15 = lane & 15, quad = lane >> 4;
  half8 w0 = *(const half8*)&Wt[(L*32 + ln15     )*XSTR + quad*8];
  half8 w1 = *(const half8*)&Wt[(L*32 + ln15 + 16)*XSTR + quad*8];
  float bias0[4], bias1[4];
#pragma unroll
  for (int reg=0;reg<4;++reg){
    bias0[reg] = Cb[L*32 +      quad*4 + reg];
    bias1[reg] = Cb[L*32 + 16 + quad*4 + reg];
  }
  int rowbase = wv*64;
#pragma unroll
  for (int Mt=0; Mt<4; ++Mt){
    int s = rowbase + Mt*16 + ln15;
    half8 bfr = *(const half8*)&X[s*XSTR + quad*8];
    f32x4 c0 = {0.f,0.f,0.f,0.f}, c1 = {0.f,0.f,0.f,0.f};
    c0 = __builtin_amdgcn_mfma_f32_16x16x32_f16(w0, bfr, c0, 0,0,0);
    c1 = __builtin_amdgcn_mfma_f32_16x16x32_f16(w1, bfr, c1, 0,0,0);
    float o0[4], o1v[4];
    if (KIND == KIND_TANHRES || KIND == KIND_TANHRES_ATREG){
      unpk4(*(const uint2*)&X[s*XSTR +      quad*4], o0);
      unpk4(*(const uint2*)&X[s*XSTR + 16 + quad*4], o1v);
    }
    float a0v[4], a1v[4];
    if (KIND == KIND_TANHRES_ATREG){
      a0v[0]=lo16(at_pk[Mt*4+0]); a0v[1]=hi16(at_pk[Mt*4+0]);
      a0v[2]=lo16(at_pk[Mt*4+1]); a0v[3]=hi16(at_pk[Mt*4+1]);
      a1v[0]=lo16(at_pk[Mt*4+2]); a1v[1]=hi16(at_pk[Mt*4+2]);
      a1v[2]=lo16(at_pk[Mt*4+3]); a1v[3]=hi16(at_pk[Mt*4+3]);
    }
    float v0[4], v1[4];
#pragma unroll
    for (int reg=0;reg<4;++reg){
      float a = c0[reg] + bias0[reg];
      float b = c1[reg] + bias1[reg];
      if (KIND == KIND_TANH){ a = tanh_fast(a); b = tanh_fast(b); }
      else if (KIND == KIND_TANHRES){ a = o0[reg] + tanh_fast(a); b = o1v[reg] + tanh_fast(b); }
      else if (KIND == KIND_TANHRES_ATREG){
        a = (o0[reg] + tanh_fast(a)) * a0v[reg];
        b = (o1v[reg] + tanh_fast(b)) * a1v[reg];
      }
      v0[reg] = a; v1[reg] = b;
    }
    uint2 w0o, w1o;
    w0o.x = pack2h(v0[0], v0[1]); w0o.y = pack2h(v0[2], v0[3]);
    w1o.x = pack2h(v1[0], v1[1]); w1o.y = pack2h(v1[2], v1[3]);
    *(uint2*)&X[s*XSTR +      quad*4] = w0o;
    *(uint2*)&X[s*XSTR + 16 + quad*4] = w1o;
  }
}

// ---------------- MFMA logits + in-register softmax -> at_pk ----------------
__device__ __forceinline__ void mfma_logits_softmax(const u16* X, const u16* Wt, const float* Cb,
    int L, int wv, int lane, const int* __restrict__ mask, int maskbase, u32* at_pk)
{
  int ln15 = lane & 15, quad = lane >> 4;
  half8 w0 = *(const half8*)&Wt[(L*32 + ln15     )*XSTR + quad*8];
  half8 w1 = *(const half8*)&Wt[(L*32 + ln15 + 16)*XSTR + quad*8];
  float bias0[4], bias1[4];
#pragma unroll
  for (int reg=0;reg<4;++reg){
    bias0[reg] = Cb[L*32 +      quad*4 + reg];
    bias1[reg] = Cb[L*32 + 16 + quad*4 + reg];
  }
  int rowbase = wv*64;
#pragma unroll
  for (int Mt=0; Mt<4; ++Mt){
    int s = rowbase + Mt*16 + ln15;
    half8 bfr = *(const half8*)&X[s*XSTR + quad*8];
    f32x4 c0 = {0.f,0.f,0.f,0.f}, c1 = {0.f,0.f,0.f,0.f};
    c0 = __builtin_amdgcn_mfma_f32_16x16x32_f16(w0, bfr, c0, 0,0,0);
    c1 = __builtin_amdgcn_mfma_f32_16x16x32_f16(w1, bfr, c1, 0,0,0);
    float l0[4], l1[4];
#pragma unroll
    for (int reg=0;reg<4;++reg){ l0[reg] = c0[reg]+bias0[reg]; l1[reg] = c1[reg]+bias1[reg]; }
    float mx = l0[0];
#pragma unroll
    for (int reg=1;reg<4;++reg) mx = fmaxf(mx, l0[reg]);
#pragma unroll
    for (int reg=0;reg<4;++reg) mx = fmaxf(mx, l1[reg]);
    mx = fmaxf(mx, __shfl_xor(mx, 16));
    mx = fmaxf(mx, __shfl_xor(mx, 32));
    float sum = 0.f;
#pragma unroll
    for (int reg=0;reg<4;++reg){ l0[reg] = __expf(l0[reg]-mx); sum += l0[reg]; }
#pragma unroll
    for (int reg=0;reg<4;++reg){ l1[reg] = __expf(l1[reg]-mx); sum += l1[reg]; }
    sum += __shfl_xor(sum, 16);
    sum += __shfl_xor(sum, 32);
    float inv = __builtin_amdgcn_rcpf(sum);
    bool mz = (mask[maskbase + Mt*16 + ln15] == 0);
#pragma unroll
    for (int reg=0;reg<4;++reg){
      l0[reg] *= inv; l1[reg] *= inv;
      if (mz){ l0[reg] = -__builtin_inff(); l1[reg] = -__builtin_inff(); }
    }
    at_pk[Mt*4+0] = pack2h(l0[0], l0[1]);
    at_pk[Mt*4+1] = pack2h(l0[2], l0[3]);
    at_pk[Mt*4+2] = pack2h(l1[0], l1[1]);
    at_pk[Mt*4+3] = pack2h(l1[2], l1[3]);
  }
}

// ---------------- column stats reducers (64-sharded atomics) ----------------
__device__ __forceinline__ void reduce_f16(const u16* X, float* lds2,
                                           float* __restrict__ S, int offS, int shard)
{
  int tid = threadIdx.x;
  __syncthreads();
  {
    int j = tid & 31, seg = tid >> 5;
    float s=0.f, q=0.f;
    for (int q2=0;q2<32;++q2){
      float v = h2f(X[(seg*32+q2)*XSTR + j]);
      s += v; q = fmaf(v,v,q);
    }
    lds2[seg*32+j] = s;
    lds2[256 + seg*32+j] = q;
  }
  __syncthreads();
  if (tid < 64){
    int j = tid & 31; bool isq = tid >= 32;
    const float* src = lds2 + (isq?256:0);
    float tot=0.f;
#pragma unroll
    for (int sg=0;sg<8;++sg) tot += src[sg*32+j];
    atomicAdd(&S[shard*SHARD + offS + (isq?32:0) + j], tot);
  }
  __syncthreads();
}

__device__ __forceinline__ void reduce_f32(const float* Xs, float* lds2,
                                           float* __restrict__ S, int offS, int shard)
{
  int tid = threadIdx.x;
  __syncthreads();
  {
    int j = tid & 31, seg = tid >> 5;
    float s=0.f, q=0.f;
    for (int q2=0;q2<32;++q2){
      float v = Xs[(seg*32+q2)*33 + j];
      s += v; q = fmaf(v,v,q);
    }
    lds2[seg*32+j] = s;
    lds2[256 + seg*32+j] = q;
  }
  __syncthreads();
  if (tid < 64){
    int j = tid & 31; bool isq = tid >= 32;
    const float* src = lds2 + (isq?256:0);
    float tot=0.f;
#pragma unroll
    for (int sg=0;sg<8;++sg) tot += src[sg*32+j];
    atomicAdd(&S[shard*SHARD + offS + (isq?32:0) + j], tot);
  }
  __syncthreads();
}

// ---------------- pass1: stats of o1, a1 (recompute, no writes) ----------------
template<bool F32>
__device__ __forceinline__ void pass1_body(const void* __restrict__ u,
    const void* pg1, const void* pb1, const void* pw1,
    const void* og1, const void* ob1, const void* ow1,
    float* __restrict__ S, float* Xs, float* lds2, float* mr)
{
  int tid = threadIdx.x;
  int r = blockIdx.x*256 + tid;
  int shard = blockIdx.x & (NSH-1);
  prep_u(S, mr, tid);
  float f[4]; load_u4<F32>(u,r,f);
  float xn[4];
  float* Xp = Xs + tid*33;

  bn_u_l<F32>(mr, pg1, pb1, f, xn);
#pragma unroll
  for (int j=0;j<32;++j)
    Xp[j] = tanh_fast(xn[0]*rdp<F32>(pw1,j*4+0) + xn[1]*rdp<F32>(pw1,j*4+1)
                    + xn[2]*rdp<F32>(pw1,j*4+2) + xn[3]*rdp<F32>(pw1,j*4+3));
  reduce_f32(Xs, lds2, S, S_O1, shard);

  bn_u_l<F32>(mr, og1, ob1, f, xn);
#pragma unroll
  for (int j=0;j<32;++j)
    Xp[j] = tanh_fast(xn[0]*rdp<F32>(ow1,j*4+0) + xn[1]*rdp<F32>(ow1,j*4+1)
                    + xn[2]*rdp<F32>(ow1,j*4+2) + xn[3]*rdp<F32>(ow1,j*4+3));
  reduce_f32(Xs, lds2, S, S_A1, shard);
}
__global__ __launch_bounds__(256) void k_pass1(const void* __restrict__ u,
    const void* pg1, const void* pb1, const void* pw1,
    const void* og1, const void* ob1, const void* ow1,
    float* __restrict__ S, const int* __restrict__ flag){
  __shared__ float Xs[256*33];
  __shared__ float lds2[512];
  __shared__ float mr[8];
  if (*flag) pass1_body<true >(u,pg1,pb1,pw1,og1,ob1,ow1,S,Xs,lds2,mr);
  else       pass1_body<false>(u,pg1,pb1,pw1,og1,ob1,ow1,S,Xs,lds2,mr);
}

// ---------------- pass2: recompute chains + MFMA; MAT writes o12g/a2g ----------------
template<bool F32, bool MAT>
__device__ __forceinline__ void pass2_body(const void* __restrict__ u,
    const void* pg1, const void* pb1, const void* pw1,
    const void* og1, const void* ob1, const void* ow1,
    const void* pg2, const void* pb2, const void* pw2,
    const void* og2, const void* ob2, const void* ow2,
    float* __restrict__ S, u16* __restrict__ o12g, u16* __restrict__ a2g,
    u16* X, u16* Wt, float* Cb, float* lds2, float* mr)
{
  int tid = threadIdx.x;
  int wv = tid >> 6, lane = tid & 63;
  int r = blockIdx.x*256 + tid;
  int shard = blockIdx.x & (NSH-1);
  prep_u(S, mr, tid);
  fold2<F32>(S, S_O1, S_A1, pg2,pb2,pw2, og2,ob2,ow2, Wt, Cb, lds2);

  float f[4], xn[4];
  load_u4<F32>(u,r,f);

  bn_u_l<F32>(mr, pg1, pb1, f, xn);
  chain1_to_lds<F32>(xn, pw1, X + tid*XSTR);              // o1
  mfma_layer<KIND_TANHRES>(X, Wt, Cb, 0, wv, lane, 0);    // o12
  if (MAT) l2grow(X, tid, o12g, r);
  reduce_f16(X, lds2, S, S_O12, shard);

  bn_u_l<F32>(mr, og1, ob1, f, xn);
  chain1_to_lds<F32>(xn, ow1, X + tid*XSTR);              // a1
  mfma_layer<KIND_TANH  >(X, Wt, Cb, 1, wv, lane, 0);     // a2
  if (MAT) l2grow(X, tid, a2g, r);
  reduce_f16(X, lds2, S, S_A2, shard);
}
template<bool MAT>
__global__ __launch_bounds__(256) void k_pass2(const void* __restrict__ u,
    const void* pg1, const void* pb1, const void* pw1,
    const void* og1, const void* ob1, const void* ow1,
    const void* pg2, const void* pb2, const void* pw2,
    const void* og2, const void* ob2, const void* ow2,
    float* __restrict__ S, u16* o12g, u16* a2g, const int* __restrict__ flag){
  __shared__ u16 X[256*XSTR];
  __shared__ u16 Wt[2*32*XSTR];
  __shared__ float Cb[64];
  __shared__ float lds2[512];
  __shared__ float mr[8];
  if (*flag) pass2_body<true ,MAT>(u,pg1,pb1,pw1,og1,ob1,ow1,pg2,pb2,pw2,og2,ob2,ow2,S,o12g,a2g,X,Wt,Cb,lds2,mr);
  else       pass2_body<false,MAT>(u,pg1,pb1,pw1,og1,ob1,ow1,pg2,pb2,pw2,og2,ob2,ow2,S,o12g,a2g,X,Wt,Cb,lds2,mr);
}

// ---------------- pass3 (MAT): load o12g/a2g, L3 layers + softmax + pool + S_X ----------------
template<bool F32>
__device__ __forceinline__ void pass3m_body(const int* __restrict__ mask,
    const void* pg3, const void* pb3, const void* pw3,
    const void* og3, const void* ob3, const void* ow3,
    const u16* __restrict__ o12g, const u16* __restrict__ a2g,
    float* __restrict__ x, float* __restrict__ S,
    u16* X, u16* Wt, float* Cb, float* red2)
{
  int tid = threadIdx.x;
  int wv = tid >> 6, lane = tid & 63;
  int r = blockIdx.x*256 + tid;
  // L0 = 3O (stats S_A2), L1 = 3P (stats S_O12)
  fold2<F32>(S, S_A2, S_O12, og3,ob3,ow3, pg3,pb3,pw3, Wt, Cb, red2);

  u32 at_pk[16];
  int maskbase = blockIdx.x*256 + wv*64;

  g2lrow(a2g, r, X, tid);
  __syncthreads();
  mfma_logits_softmax(X, Wt, Cb, 0, wv, lane, mask, maskbase, at_pk);
  __syncthreads();
  g2lrow(o12g, r, X, tid);
  __syncthreads();
  mfma_layer<KIND_TANHRES_ATREG>(X, Wt, Cb, 1, wv, lane, at_pk); // xm*at

  __syncthreads();
  {
    int jj = tid & 31, cgrp = (tid >> 5) & 3, half = tid >> 7;
    float s2 = 0.f;
    for (int q2=0;q2<32;++q2) s2 += h2f(X[(half*128 + cgrp*32 + q2)*XSTR + jj]);
    red2[tid] = s2;
  }
  __syncthreads();
  if (tid < 64){
    int half = tid >> 5, j = tid & 31;
    float v = red2[half*128+j] + red2[half*128+32+j] + red2[half*128+64+j] + red2[half*128+96+j];
    x[(blockIdx.x*2 + half)*32 + j] = v;
    float* Sh = S + (blockIdx.x & (NSH-1))*SHARD;
    atomicAdd(&Sh[S_X+j], v);
    atomicAdd(&Sh[S_X+32+j], v*v);
  }
}
__global__ __launch_bounds__(256) void k_pass3m(const int* __restrict__ mask,
    const void* pg3, const void* pb3, const void* pw3,
    const void* og3, const void* ob3, const void* ow3,
    const u16* o12g, const u16* a2g,
    float* __restrict__ x, float* __restrict__ S, const int* __restrict__ flag){
  __shared__ u16 X [256*XSTR];
  __shared__ u16 Wt[2*32*XSTR];
  __shared__ float Cb[64];
  __shared__ float red2[256];
  if (*flag) pass3m_body<true >(mask,pg3,pb3,pw3,og3,ob3,ow3,o12g,a2g,x,S,X,Wt,Cb,red2);
  else       pass3m_body<false>(mask,pg3,pb3,pw3,og3,ob3,ow3,o12g,a2g,x,S,X,Wt,Cb,red2);
}

// ---------------- pass3 (fallback, full recompute) ----------------
template<bool F32>
__device__ __forceinline__ void fold4(const float* __restrict__ S,
    int off0,int off1,int off2,int off3,
    const void* g0,const void* b0,const void* W0,
    const void* g1,const void* b1,const void* W1,
    const void* g2,const void* b2,const void* W2,
    const void* g3,const void* b3,const void* W3,
    u16* Wt, float* Cb, float* scr)
{
  int tid = threadIdx.x;
  __shared__ float scr2[256];
  if (tid < 128){
    int L = tid>>5, k = tid&31;
    const void* g = (L==0)?g0:(L==1)?g1:(L==2)?g2:g3;
    const void* b = (L==0)?b0:(L==1)?b1:(L==2)?b2:b3;
    int off = (L==0)?off0:(L==1)?off1:(L==2)?off2:off3;
    float s=0.f, q=0.f;
    for (int sh=0; sh<NSH; ++sh){
      s += S[sh*SHARD + off + k];
      q += S[sh*SHARD + off + 32 + k];
    }
    float m    = s*(1.0f/ROWS);
    float var  = q*(1.0f/ROWS) - m*m;
    float rstd = rsqrtf(var+EPS);
    float sc = rdp<F32>(g,k)*rstd;
    scr[tid]  = sc;
    scr2[tid] = rdp<F32>(b,k) - m*sc;
  }
  __syncthreads();
  if (tid < 128){
    int L = tid>>5, j = tid&31;
    const void* W = (L==0)?W0:(L==1)?W1:(L==2)?W2:W3;
    float c = 0.f;
#pragma unroll
    for (int k=0;k<32;++k){
      float Wv = rdp<F32>(W, j*32+k);
      Wt[(L*32+j)*XSTR + k] = f2h(Wv * scr[(L<<5)|k]);
      c += Wv * scr2[(L<<5)|k];
    }
    Cb[L*32+j] = c;
  }
  __syncthreads();
}

template<bool F32>
__device__ __forceinline__ void pass3_body(const void* __restrict__ u, const int* __restrict__ mask,
    const void* pg1, const void* pb1, const void* pw1,
    const void* og1, const void* ob1, const void* ow1,
    const void* pg2, const void* pb2, const void* pw2,
    const void* og2, const void* ob2, const void* ow2,
    const void* pg3, const void* pb3, const void* pw3,
    const void* og3, const void* ob3, const void* ow3,
    float* __restrict__ x, float* __restrict__ S,
    u16* X, u16* Wt, float* Cb, float* red2, float* mr)
{
  int tid = threadIdx.x;
  int wv = tid >> 6, lane = tid & 63;
  int r = blockIdx.x*256 + tid;
  prep_u(S, mr, tid);
  fold4<F32>(S, S_A1, S_A2, S_O1, S_O12,
             og2,ob2,ow2, og3,ob3,ow3, pg2,pb2,pw2, pg3,pb3,pw3,
             Wt, Cb, red2);

  float f[4], xn[4];
  load_u4<F32>(u,r,f);
  u32 at_pk[16];
  int maskbase = blockIdx.x*256 + wv*64;

  bn_u_l<F32>(mr, og1, ob1, f, xn);
  chain1_to_lds<F32>(xn, ow1, X + tid*XSTR);
  mfma_layer<KIND_TANH>(X, Wt, Cb, 0, wv, lane, 0);
  mfma_logits_softmax(X, Wt, Cb, 1, wv, lane, mask, maskbase, at_pk);

  bn_u_l<F32>(mr, pg1, pb1, f, xn);
  chain1_to_lds<F32>(xn, pw1, X + tid*XSTR);
  mfma_layer<KIND_TANHRES   >(X, Wt, Cb, 2, wv, lane, 0);
  mfma_layer<KIND_TANHRES_ATREG>(X, Wt, Cb, 3, wv, lane, at_pk);

  __syncthreads();
  {
    int jj = tid & 31, cgrp = (tid >> 5) & 3, half = tid >> 7;
    float s2 = 0.f;
    for (int q2=0;q2<32;++q2) s2 += h2f(X[(half*128 + cgrp*32 + q2)*XSTR + jj]);
    red2[tid] = s2;
  }
  __syncthreads();
  if (tid < 64){
    int half = tid >> 5, j = tid & 31;
    float v = red2[half*128+j] + red2[half*128+32+j] + red2[half*128+64+j] + red2[half*128+96+j];
    x[(blockIdx.x*2 + half)*32 + j] = v;
    float* Sh = S + (blockIdx.x & (NSH-1))*SHARD;
    atomicAdd(&Sh[S_X+j], v);
    atomicAdd(&Sh[S_X+32+j], v*v);
  }
}
__global__ __launch_bounds__(256) void k_pass3(const void* __restrict__ u, const int* __restrict__ mask,
    const void* pg1, const void* pb1, const void* pw1,
    const void* og1, const void* ob1, const void* ow1,
    const void* pg2, const void* pb2, const void* pw2,
    const void* og2, const void* ob2, const void* ow2,
    const void* pg3, const void* pb3, const void* pw3,
    const void* og3, const void* ob3, const void* ow3,
    float* __restrict__ x, float* __restrict__ S, const int* __restrict__ flag){
  __shared__ u16 X [256*XSTR];
  __shared__ u16 Wt[4*32*XSTR];
  __shared__ float Cb[128];
  __shared__ float red2[256];
  __shared__ float mr[8];
  if (*flag) pass3_body<true >(u,mask,pg1,pb1,pw1,og1,ob1,ow1,pg2,pb2,pw2,og2,ob2,ow2,
                               pg3,pb3,pw3,og3,ob3,ow3,x,S,X,Wt,Cb,red2,mr);
  else       pass3_body<false>(u,mask,pg1,pb1,pw1,og1,ob1,ow1,pg2,pb2,pw2,og2,ob2,ow2,
                               pg3,pb3,pw3,og3,ob3,ow3,x,S,X,Wt,Cb,red2,mr);
}

// ---------------- theta layer (preamble stats, two-stage reduce) ----------------
template<bool F32>
__device__ __forceinline__ void theta_body(const float* __restrict__ X, float* __restrict__ S, int offin,
    const void* g, const void* bt, const void* W, float* __restrict__ Y, int offout,
    float* lds, float* lds2)
{
  int r = blockIdx.x*blockDim.x + threadIdx.x;   // 4096 rows exactly
  int tid = threadIdx.x;
  int shard = blockIdx.x & (NSH-1);
  if (tid < 32){
    float s=0.f, q=0.f;
    for (int sh=0; sh<NSH; ++sh){
      s += S[sh*SHARD + offin + tid];
      q += S[sh*SHARD + offin + 32 + tid];
    }
    float m = s*(1.0f/BROWS);
    float var = q*(1.0f/BROWS) - m*m;
    lds2[tid]    = m;
    lds2[32+tid] = rsqrtf(var + EPS);
  }
  __syncthreads();
  float* Xp = lds + tid*33;
#pragma unroll
  for (int k=0;k<32;++k){
    Xp[k] = (X[(size_t)r*32+k] - lds2[k]) * (rdp<F32>(g,k)*lds2[32+k]) + rdp<F32>(bt,k);
  }
  float out[32];
#pragma unroll
  for (int j=0;j<32;++j){
    float acc = 0.f;
#pragma unroll
    for (int k=0;k<32;++k) acc = fmaf(rdp<F32>(W, j*32+k), Xp[k], acc);
    out[j] = tanh_fast(acc);
    Y[(size_t)r*32+j] = out[j];
  }
  __syncthreads();
#pragma unroll
  for (int j=0;j<32;++j) Xp[j] = out[j];
  reduce_f32(lds, lds2, S, offout, shard);
}
__global__ __launch_bounds__(256) void k_theta(const float* X, float* S, int offin,
    const void* g, const void* bt, const void* W, float* Y, int offout, const int* __restrict__ flag){
  __shared__ float lds[256*33];
  __shared__ float lds2[512];
  if (*flag) theta_body<true >(X,S,offin,g,bt,W,Y,offout,lds,lds2);
  else       theta_body<false>(X,S,offin,g,bt,W,Y,offout,lds,lds2);
}

// ---------------- final layer ----------------
template<bool F32>
__device__ __forceinline__ void theta4_body(const float* __restrict__ X, const float* __restrict__ S, int offin,
    const void* g, const void* bt, const void* w4, const void* b4, void* out, float* ms)
{
  int r = blockIdx.x*blockDim.x + threadIdx.x;
  int tid = threadIdx.x;
  if (tid < 32){
    float s=0.f, q=0.f;
    for (int sh=0; sh<NSH; ++sh){
      s += S[sh*SHARD + offin + tid];
      q += S[sh*SHARD + offin + 32 + tid];
    }
    float m = s*(1.0f/BROWS);
    float var = q*(1.0f/BROWS) - m*m;
    ms[tid]    = m;
    ms[32+tid] = rsqrtf(var + EPS);
  }
  __syncthreads();
  float acc = rdp<F32>(b4, 0);
#pragma unroll
  for (int k=0;k<32;++k){
    float xnv = (X[(size_t)r*32+k] - ms[k]) * (rdp<F32>(g,k)*ms[32+k]) + rdp<F32>(bt,k);
    acc = fmaf(rdp<F32>(w4,k), xnv, acc);
  }
  if (F32) ((float*)out)[r] = acc;
  else     ((u16*)out)[r]  = f2b(acc);
}
__global__ __launch_bounds__(256) void k_theta4(const float* X, const float* S, int offin,
    const void* g, const void* bt, const void* w4, const void* b4, void* out, const int* __restrict__ flag){
  __shared__ float ms[64];
  if (*flag) theta4_body<true >(X,S,offin,g,bt,w4,b4,out,ms);
  else       theta4_body<false>(X,S,offin,g,bt,w4,b4,out,ms);
}

extern "C" void kernel_launch(void* const* d_in, const int* in_sizes, int n_in,
                              void* d_out, int out_size, void* d_ws, size_t ws_size,
                              hipStream_t stream)
{
  const void* u    = d_in[0];
  const int*  mask = (const int*)d_in[1];
  const void *pg1=d_in[2],  *pb1=d_in[3],  *pw1=d_in[4];
  const void *pg2=d_in[5],  *pb2=d_in[6],  *pw2=d_in[7];
  const void *pg3=d_in[8],  *pb3=d_in[9],  *pw3=d_in[10];
  const void *og1=d_in[11], *ob1=d_in[12], *ow1=d_in[13];
  const void *og2=d_in[14], *ob2=d_in[15], *ow2=d_in[16];
  const void *og3=d_in[17], *ob3=d_in[18], *ow3=d_in[19];
  const void *tg1=d_in[20], *tb1=d_in[21], *tw1=d_in[22];
  const void *tg2=d_in[23], *tb2=d_in[24], *tw2=d_in[25];
  const void *tg3=d_in[26], *tb3=d_in[27], *tw3=d_in[28];
  const void *tg4=d_in[29], *tb4=d_in[30], *tw4=d_in[31], *tbb4=d_in[32];

  char* ws = (char*)d_ws;
  int*   flag = (int*)ws;                    // byte 0
  float* S    = (float*)(ws + 4096);         // 64 shards x 1024 floats = 256 KB
  float* x    = (float*)(ws + 524288);       // 4096*32 f32 x4
  float* x1 = x  + BROWS*32;
  float* x2 = x1 + BROWS*32;
  float* x3 = x2 + BROWS*32;

  const size_t MB = 1024*1024;
  u16* o12g = (u16*)(ws + 8*MB);             // 32 MB each
  u16* a2g  = (u16*)(ws + 40*MB);
  bool MAT = ws_size >= 73*MB;               // constant per process -> graph-safe

  (void)hipMemsetAsync(ws, 0, 4096 + NSH*SHARD*4, stream);  // zero flag + sharded stats
  k_detect<<<1, 64, 0, stream>>>((const u16*)u, flag);
  k_stats_u<<<1024, 256, 0, stream>>>(u, S, flag);
  k_pass1<<<2048, 256, 0, stream>>>(u, pg1,pb1,pw1, og1,ob1,ow1, S, flag);
  if (MAT){
    k_pass2<true ><<<2048, 256, 0, stream>>>(u, pg1,pb1,pw1, og1,ob1,ow1,
                                             pg2,pb2,pw2, og2,ob2,ow2, S, o12g, a2g, flag);
    k_pass3m<<<2048, 256, 0, stream>>>(mask, pg3,pb3,pw3, og3,ob3,ow3, o12g, a2g, x, S, flag);
  } else {
    k_pass2<false><<<2048, 256, 0, stream>>>(u, pg1,pb1,pw1, og1,ob1,ow1,
                                             pg2,pb2,pw2, og2,ob2,ow2, S, o12g, a2g, flag);
    k_pass3<<<2048, 256, 0, stream>>>(u, mask, pg1,pb1,pw1, og1,ob1,ow1,
                                      pg2,pb2,pw2, og2,ob2,ow2,
                                      pg3,pb3,pw3, og3,ob3,ow3, x, S, flag);
  }
  k_theta<<<16, 256, 0, stream>>>(x,  S, S_X,  tg1,tb1,tw1, x1, S_X1, flag);
  k_theta<<<16, 256, 0, stream>>>(x1, S, S_X1, tg2,tb2,tw2, x2, S_X2, flag);
  k_theta<<<16, 256, 0, stream>>>(x2, S, S_X2, tg3,tb3,tw3, x3, S_X3, flag);
  k_theta4<<<16, 256, 0, stream>>>(x3, S, S_X3, tg4,tb4,tw4,tbb4, d_out, flag);
}

// Round 15
// 318.208 us; speedup vs baseline: 1.0657x; 1.0422x over previous
//
#include <hip/hip_runtime.h>

typedef unsigned int u32;
typedef unsigned short u16;
typedef __attribute__((ext_vector_type(8))) _Float16 half8;
typedef __attribute__((ext_vector_type(4))) float f32x4;

#define ROWS  524288   // B*N
#define BROWS 4096     // B
#define EPS   1e-5f

// ---- stats: 64 shards of 1024 floats; block-coop summing ----
#define S_U   0
#define S_O1  8
#define S_A1  72
#define S_O12 136
#define S_A2  200
#define S_X   264
#define S_X1  328
#define S_X2  392
#define S_X3  456
#define SHARD 1024
#define NSH   64

#define XSTR 40   // LDS row stride in u16

__device__ __forceinline__ float bl(u32 u){ return __uint_as_float(u << 16); }
__device__ __forceinline__ float bh(u32 u){ return __uint_as_float(u & 0xFFFF0000u); }
__device__ __forceinline__ float b2f(u16 h){ return __uint_as_float(((u32)h) << 16); }
__device__ __forceinline__ u16 f2b(float f){
  u32 u = __float_as_uint(f);
  return (u16)((u + 0x7FFFu + ((u >> 16) & 1u)) >> 16);   // RNE (bf16, output only)
}
__device__ __forceinline__ u16 f2h(float f){ _Float16 h = (_Float16)f; return __builtin_bit_cast(u16, h); }
__device__ __forceinline__ float h2f(u16 x){ return (float)__builtin_bit_cast(_Float16, x); }
__device__ __forceinline__ u32 pack2h(float a, float b){
  auto v = __builtin_amdgcn_cvt_pkrtz(a, b);
  return __builtin_bit_cast(u32, v);
}
__device__ __forceinline__ float lo16(u32 w){ return h2f((u16)(w & 0xFFFF)); }
__device__ __forceinline__ float hi16(u32 w){ return h2f((u16)(w >> 16)); }
__device__ __forceinline__ void unpk4(uint2 v, float* d){
  d[0]=lo16(v.x); d[1]=hi16(v.x); d[2]=lo16(v.y); d[3]=hi16(v.y);
}

// Padé(5,4) tanh: no v_exp; err <= ~1e-3, clamped to [-1,1].
__device__ __forceinline__ float tanh_fast(float x){
  float x2 = x*x;
  float num = fmaf(x2 + 105.0f, x2, 945.0f) * x;
  float den = fmaf(fmaf(x2, 15.0f, 420.0f), x2, 945.0f);
  float v = num * __builtin_amdgcn_rcpf(den);
  return fminf(1.0f, fmaxf(-1.0f, v));
}

template<bool F32>
__device__ __forceinline__ float rdp(const void* p, int i){
  if (F32) return ((const float*)p)[i];
  return b2f(((const u16*)p)[i]);
}
template<bool F32>
__device__ __forceinline__ void load_u4(const void* u, int r, float* f){
  if (F32){
    float4 v = ((const float4*)u)[r];
    f[0]=v.x; f[1]=v.y; f[2]=v.z; f[3]=v.w;
  } else {
    uint2 v = ((const uint2*)u)[r];
    f[0]=bl(v.x); f[1]=bh(v.x); f[2]=bl(v.y); f[3]=bh(v.y);
  }
}

// ---- per-block inline dtype detect (replaces k_detect + global flag) ----
// fp32 data read as halfwords: low-mantissa halves have ~uniform high exponents.
__device__ __forceinline__ int detect_u(const u16* __restrict__ u, int tid, int* sf){
  if (tid < 64){
    int bad = 0;
#pragma unroll
    for (int i = 0; i < 4; ++i){
      int e = (u[tid*4 + i] >> 7) & 0xFF;
      bad += (e >= 0x90) ? 1 : 0;
    }
#pragma unroll
    for (int off = 32; off >= 1; off >>= 1) bad += __shfl_down(bad, off);
    if (tid == 0) *sf = (bad >= 4) ? 1 : 0;
  }
  __syncthreads();
  return *sf;
}

// ---- device-scope spin barrier (grid co-resident by construction) ----
__device__ __forceinline__ void gbar(u32* ctr, int tid, u32 nblk){
  __threadfence();
  __syncthreads();
  if (tid == 0){
    __hip_atomic_fetch_add(ctr, 1u, __ATOMIC_ACQ_REL, __HIP_MEMORY_SCOPE_AGENT);
    while (__hip_atomic_load(ctr, __ATOMIC_ACQUIRE, __HIP_MEMORY_SCOPE_AGENT) < nblk){
      __builtin_amdgcn_s_sleep(8);
    }
  }
  __syncthreads();
  __threadfence();
}

// ---- LDS row <-> global f16 tensor ----
__device__ __forceinline__ void g2lrow(const u16* __restrict__ g, int r, u16* X, int tid){
  const uint4* src = (const uint4*)&g[(size_t)r*32];
  uint4* dst = (uint4*)&X[tid*XSTR];
#pragma unroll
  for (int c=0;c<4;++c) dst[c] = src[c];
}
__device__ __forceinline__ void l2grow(const u16* X, int tid, u16* __restrict__ g, int r){
  const uint4* src = (const uint4*)&X[tid*XSTR];
  uint4* dst = (uint4*)&g[(size_t)r*32];
#pragma unroll
  for (int c=0;c<4;++c) dst[c] = src[c];
}

// ---------------- stats of u (4 cols) ----------------
template<bool F32>
__device__ __forceinline__ void stats_u_body(const void* __restrict__ u, float* __restrict__ S){
  int tid = blockIdx.x*blockDim.x + threadIdx.x;
  int nt  = gridDim.x*blockDim.x;
  float s[4]={0,0,0,0}, q[4]={0,0,0,0};
  for (int r = tid; r < ROWS; r += nt){
    float f[4]; load_u4<F32>(u, r, f);
#pragma unroll
    for (int k=0;k<4;++k){ s[k]+=f[k]; q[k]+=f[k]*f[k]; }
  }
#pragma unroll
  for (int off=32; off>=1; off>>=1){
#pragma unroll
    for (int k=0;k<4;++k){ s[k]+=__shfl_down(s[k],off); q[k]+=__shfl_down(q[k],off); }
  }
  if ((threadIdx.x & 63) == 0){
    float* Sh = S + (blockIdx.x & (NSH-1))*SHARD;
#pragma unroll
    for (int k=0;k<4;++k){ atomicAdd(&Sh[S_U+k], s[k]); atomicAdd(&Sh[S_U+4+k], q[k]); }
  }
}
__global__ __launch_bounds__(256) void k_stats_u(const void* __restrict__ u, float* __restrict__ S){
  __shared__ int sf;
  int isf = detect_u((const u16*)u, threadIdx.x, &sf);
  if (isf) stats_u_body<true>(u,S); else stats_u_body<false>(u,S);
}

// ---------------- block preamble: m/rstd of u ----------------
__device__ __forceinline__ void prep_u(const float* __restrict__ S, float* mr, int tid){
  if (tid < 4){
    float s=0.f, q=0.f;
    for (int sh=0; sh<NSH; ++sh){
      s += S[sh*SHARD + S_U + tid];
      q += S[sh*SHARD + S_U + 4 + tid];
    }
    float m = s*(1.0f/ROWS);
    float var = q*(1.0f/ROWS) - m*m;
    mr[tid]   = m;
    mr[4+tid] = rsqrtf(var + EPS);
  }
  __syncthreads();
}
template<bool F32>
__device__ __forceinline__ void bn_u_l(const float* mr, const void* g, const void* b,
                                       const float* f, float* xn){
#pragma unroll
  for (int k=0;k<4;++k)
    xn[k] = (f[k]-mr[k])*(rdp<F32>(g,k)*mr[4+k]) + rdp<F32>(b,k);
}

// ---------------- L1 chain -> f16 LDS row ----------------
template<bool F32>
__device__ __forceinline__ void chain1_to_lds(const float* xn, const void* W1, u16* Xrow){
  u32 buf[16];
#pragma unroll
  for (int jp=0; jp<16; ++jp){
    int j0 = 2*jp, j1 = 2*jp+1;
    float a0 = tanh_fast(xn[0]*rdp<F32>(W1,j0*4+0) + xn[1]*rdp<F32>(W1,j0*4+1)
                       + xn[2]*rdp<F32>(W1,j0*4+2) + xn[3]*rdp<F32>(W1,j0*4+3));
    float a1 = tanh_fast(xn[0]*rdp<F32>(W1,j1*4+0) + xn[1]*rdp<F32>(W1,j1*4+1)
                       + xn[2]*rdp<F32>(W1,j1*4+2) + xn[3]*rdp<F32>(W1,j1*4+3));
    buf[jp] = pack2h(a0, a1);
  }
#pragma unroll
  for (int c=0;c<4;++c){
    uint4 v; v.x = buf[c*4]; v.y = buf[c*4+1]; v.z = buf[c*4+2]; v.w = buf[c*4+3];
    *(uint4*)&Xrow[c*8] = v;
  }
}

// ---------------- in-block BN+Linear folds (64-shard summing) ----------------
template<bool F32>
__device__ __forceinline__ void fold2(const float* __restrict__ S, int offA, int offB,
    const void* gA, const void* bA, const void* WA,
    const void* gB, const void* bB, const void* WB,
    u16* Wt, float* Cb, float* scr /* >=128 floats */)
{
  int tid = threadIdx.x;
  if (tid < 64){
    int L = tid>>5, k = tid&31;
    const void* g = L? gB:gA; const void* b = L? bB:bA;
    int off = L? offB:offA;
    float s=0.f, q=0.f;
    for (int sh=0; sh<NSH; ++sh){
      s += S[sh*SHARD + off + k];
      q += S[sh*SHARD + off + 32 + k];
    }
    float m    = s*(1.0f/ROWS);
    float var  = q*(1.0f/ROWS) - m*m;
    float rstd = rsqrtf(var+EPS);
    float sc = rdp<F32>(g,k)*rstd;
    scr[tid]    = sc;
    scr[64+tid] = rdp<F32>(b,k) - m*sc;
  }
  __syncthreads();
  if (tid < 64){
    int L = tid>>5, j = tid&31;
    const void* W = L? WB:WA;
    float c = 0.f;
#pragma unroll
    for (int k=0;k<32;++k){
      float Wv = rdp<F32>(W, j*32+k);
      Wt[(L*32+j)*XSTR + k] = f2h(Wv * scr[(L<<5)|k]);
      c += Wv * scr[64 + ((L<<5)|k)];
    }
    Cb[L*32+j] = c;
  }
  __syncthreads();
}

// ---------------- MFMA layer: Y^T = W.X^T ----------------
#define KIND_TANH          0
#define KIND_TANHRES       2
#define KIND_TANHRES_ATREG 3
template<int KIND>
__device__ __forceinline__ void mfma_layer(u16* X, const u16* Wt, const float* Cb,
                                           int L, int wv, int lane, const u32* at_pk)
{
  int ln15 = lane & 15, quad = lane >> 4;
  half8 w0 = *(const half8*)&Wt[(L*32 + ln15     )*XSTR + quad*8];
  half8 w1 = *(const half8*)&Wt[(L*32 + ln15 + 16)*XSTR + quad*8];
  float bias0[4], bias1[4];
#pragma unroll
  for (int reg=0;reg<4;++reg){
    bias0[reg] = Cb[L*32 +      quad*4 + reg];
    bias1[reg] = Cb[L*32 + 16 + quad*4 + reg];
  }
  int rowbase = wv*64;
#pragma unroll
  for (int Mt=0; Mt<4; ++Mt){
    int s = rowbase + Mt*16 + ln15;
    half8 bfr = *(const half8*)&X[s*XSTR + quad*8];
    f32x4 c0 = {0.f,0.f,0.f,0.f}, c1 = {0.f,0.f,0.f,0.f};
    c0 = __builtin_amdgcn_mfma_f32_16x16x32_f16(w0, bfr, c0, 0,0,0);
    c1 = __builtin_amdgcn_mfma_f32_16x16x32_f16(w1, bfr, c1, 0,0,0);
    float o0[4], o1v[4];
    if (KIND == KIND_TANHRES || KIND == KIND_TANHRES_ATREG){
      unpk4(*(const uint2*)&X[s*XSTR +      quad*4], o0);
      unpk4(*(const uint2*)&X[s*XSTR + 16 + quad*4], o1v);
    }
    float a0v[4], a1v[4];
    if (KIND == KIND_TANHRES_ATREG){
      a0v[0]=lo16(at_pk[Mt*4+0]); a0v[1]=hi16(at_pk[Mt*4+0]);
      a0v[2]=lo16(at_pk[Mt*4+1]); a0v[3]=hi16(at_pk[Mt*4+1]);
      a1v[0]=lo16(at_pk[Mt*4+2]); a1v[1]=hi16(at_pk[Mt*4+2]);
      a1v[2]=lo16(at_pk[Mt*4+3]); a1v[3]=hi16(at_pk[Mt*4+3]);
    }
    float v0[4], v1[4];
#pragma unroll
    for (int reg=0;reg<4;++reg){
      float a = c0[reg] + bias0[reg];
      float b = c1[reg] + bias1[reg];
      if (KIND == KIND_TANH){ a = tanh_fast(a); b = tanh_fast(b); }
      else if (KIND == KIND_TANHRES){ a = o0[reg] + tanh_fast(a); b = o1v[reg] + tanh_fast(b); }
      else if (KIND == KIND_TANHRES_ATREG){
        a = (o0[reg] + tanh_fast(a)) * a0v[reg];
        b = (o1v[reg] + tanh_fast(b)) * a1v[reg];
      }
      v0[reg] = a; v1[reg] = b;
    }
    uint2 w0o, w1o;
    w0o.x = pack2h(v0[0], v0[1]); w0o.y = pack2h(v0[2], v0[3]);
    w1o.x = pack2h(v1[0], v1[1]); w1o.y = pack2h(v1[2], v1[3]);
    *(uint2*)&X[s*XSTR +      quad*4] = w0o;
    *(uint2*)&X[s*XSTR + 16 + quad*4] = w1o;
  }
}

// ---------------- MFMA logits + in-register softmax -> at_pk ----------------
__device__ __forceinline__ void mfma_logits_softmax(const u16* X, const u16* Wt, const float* Cb,
    int L, int wv, int lane, const int* __restrict__ mask, int maskbase, u32* at_pk)
{
  int ln15 = lane & 15, quad = lane >> 4;
  half8 w0 = *(const half8*)&Wt[(L*32 + ln15     )*XSTR + quad*8];
  half8 w1 = *(const half8*)&Wt[(L*32 + ln15 + 16)*XSTR + quad*8];
  float bias0[4], bias1[4];
#pragma unroll
  for (int reg=0;reg<4;++reg){
    bias0[reg] = Cb[L*32 +      quad*4 + reg];
    bias1[reg] = Cb[L*32 + 16 + quad*4 + reg];
  }
  int rowbase = wv*64;
#pragma unroll
  for (int Mt=0; Mt<4; ++Mt){
    int s = rowbase + Mt*16 + ln15;
    half8 bfr = *(const half8*)&X[s*XSTR + quad*8];
    f32x4 c0 = {0.f,0.f,0.f,0.f}, c1 = {0.f,0.f,0.f,0.f};
    c0 = __builtin_amdgcn_mfma_f32_16x16x32_f16(w0, bfr, c0, 0,0,0);
    c1 = __builtin_amdgcn_mfma_f32_16x16x32_f16(w1, bfr, c1, 0,0,0);
    float l0[4], l1[4];
#pragma unroll
    for (int reg=0;reg<4;++reg){ l0[reg] = c0[reg]+bias0[reg]; l1[reg] = c1[reg]+bias1[reg]; }
    float mx = l0[0];
#pragma unroll
    for (int reg=1;reg<4;++reg) mx = fmaxf(mx, l0[reg]);
#pragma unroll
    for (int reg=0;reg<4;++reg) mx = fmaxf(mx, l1[reg]);
    mx = fmaxf(mx, __shfl_xor(mx, 16));
    mx = fmaxf(mx, __shfl_xor(mx, 32));
    float sum = 0.f;
#pragma unroll
    for (int reg=0;reg<4;++reg){ l0[reg] = __expf(l0[reg]-mx); sum += l0[reg]; }
#pragma unroll
    for (int reg=0;reg<4;++reg){ l1[reg] = __expf(l1[reg]-mx); sum += l1[reg]; }
    sum += __shfl_xor(sum, 16);
    sum += __shfl_xor(sum, 32);
    float inv = __builtin_amdgcn_rcpf(sum);
    bool mz = (mask[maskbase + Mt*16 + ln15] == 0);
#pragma unroll
    for (int reg=0;reg<4;++reg){
      l0[reg] *= inv; l1[reg] *= inv;
      if (mz){ l0[reg] = -__builtin_inff(); l1[reg] = -__builtin_inff(); }
    }
    at_pk[Mt*4+0] = pack2h(l0[0], l0[1]);
    at_pk[Mt*4+1] = pack2h(l0[2], l0[3]);
    at_pk[Mt*4+2] = pack2h(l1[0], l1[1]);
    at_pk[Mt*4+3] = pack2h(l1[2], l1[3]);
  }
}

// ---------------- column stats reducers (64-sharded atomics) ----------------
__device__ __forceinline__ void reduce_f16(const u16* X, float* lds2,
                                           float* __restrict__ S, int offS, int shard)
{
  int tid = threadIdx.x;
  __syncthreads();
  {
    int j = tid & 31, seg = tid >> 5;
    float s=0.f, q=0.f;
    for (int q2=0;q2<32;++q2){
      float v = h2f(X[(seg*32+q2)*XSTR + j]);
      s += v; q = fmaf(v,v,q);
    }
    lds2[seg*32+j] = s;
    lds2[256 + seg*32+j] = q;
  }
  __syncthreads();
  if (tid < 64){
    int j = tid & 31; bool isq = tid >= 32;
    const float* src = lds2 + (isq?256:0);
    float tot=0.f;
#pragma unroll
    for (int sg=0;sg<8;++sg) tot += src[sg*32+j];
    atomicAdd(&S[shard*SHARD + offS + (isq?32:0) + j], tot);
  }
  __syncthreads();
}

__device__ __forceinline__ void reduce_f32(const float* Xs, float* lds2,
                                           float* __restrict__ S, int offS, int shard)
{
  int tid = threadIdx.x;
  __syncthreads();
  {
    int j = tid & 31, seg = tid >> 5;
    float s=0.f, q=0.f;
    for (int q2=0;q2<32;++q2){
      float v = Xs[(seg*32+q2)*33 + j];
      s += v; q = fmaf(v,v,q);
    }
    lds2[seg*32+j] = s;
    lds2[256 + seg*32+j] = q;
  }
  __syncthreads();
  if (tid < 64){
    int j = tid & 31; bool isq = tid >= 32;
    const float* src = lds2 + (isq?256:0);
    float tot=0.f;
#pragma unroll
    for (int sg=0;sg<8;++sg) tot += src[sg*32+j];
    atomicAdd(&S[shard*SHARD + offS + (isq?32:0) + j], tot);
  }
  __syncthreads();
}

// ---------------- pass1: stats of o1, a1 (recompute, no writes) ----------------
template<bool F32>
__device__ __forceinline__ void pass1_body(const void* __restrict__ u,
    const void* pg1, const void* pb1, const void* pw1,
    const void* og1, const void* ob1, const void* ow1,
    float* __restrict__ S, float* Xs, float* lds2, float* mr)
{
  int tid = threadIdx.x;
  int r = blockIdx.x*256 + tid;
  int shard = blockIdx.x & (NSH-1);
  prep_u(S, mr, tid);
  float f[4]; load_u4<F32>(u,r,f);
  float xn[4];
  float* Xp = Xs + tid*33;

  bn_u_l<F32>(mr, pg1, pb1, f, xn);
#pragma unroll
  for (int j=0;j<32;++j)
    Xp[j] = tanh_fast(xn[0]*rdp<F32>(pw1,j*4+0) + xn[1]*rdp<F32>(pw1,j*4+1)
                    + xn[2]*rdp<F32>(pw1,j*4+2) + xn[3]*rdp<F32>(pw1,j*4+3));
  reduce_f32(Xs, lds2, S, S_O1, shard);

  bn_u_l<F32>(mr, og1, ob1, f, xn);
#pragma unroll
  for (int j=0;j<32;++j)
    Xp[j] = tanh_fast(xn[0]*rdp<F32>(ow1,j*4+0) + xn[1]*rdp<F32>(ow1,j*4+1)
                    + xn[2]*rdp<F32>(ow1,j*4+2) + xn[3]*rdp<F32>(ow1,j*4+3));
  reduce_f32(Xs, lds2, S, S_A1, shard);
}
__global__ __launch_bounds__(256) void k_pass1(const void* __restrict__ u,
    const void* pg1, const void* pb1, const void* pw1,
    const void* og1, const void* ob1, const void* ow1,
    float* __restrict__ S){
  __shared__ float Xs[256*33];
  __shared__ float lds2[512];
  __shared__ float mr[8];
  __shared__ int sf;
  int isf = detect_u((const u16*)u, threadIdx.x, &sf);
  if (isf) pass1_body<true >(u,pg1,pb1,pw1,og1,ob1,ow1,S,Xs,lds2,mr);
  else     pass1_body<false>(u,pg1,pb1,pw1,og1,ob1,ow1,S,Xs,lds2,mr);
}

// ---------------- pass2: recompute chains + MFMA; MAT writes o12g/a2g ----------------
template<bool F32, bool MAT>
__device__ __forceinline__ void pass2_body(const void* __restrict__ u,
    const void* pg1, const void* pb1, const void* pw1,
    const void* og1, const void* ob1, const void* ow1,
    const void* pg2, const void* pb2, const void* pw2,
    const void* og2, const void* ob2, const void* ow2,
    float* __restrict__ S, u16* __restrict__ o12g, u16* __restrict__ a2g,
    u16* X, u16* Wt, float* Cb, float* lds2, float* mr)
{
  int tid = threadIdx.x;
  int wv = tid >> 6, lane = tid & 63;
  int r = blockIdx.x*256 + tid;
  int shard = blockIdx.x & (NSH-1);
  prep_u(S, mr, tid);
  fold2<F32>(S, S_O1, S_A1, pg2,pb2,pw2, og2,ob2,ow2, Wt, Cb, lds2);

  float f[4], xn[4];
  load_u4<F32>(u,r,f);

  bn_u_l<F32>(mr, pg1, pb1, f, xn);
  chain1_to_lds<F32>(xn, pw1, X + tid*XSTR);              // o1
  mfma_layer<KIND_TANHRES>(X, Wt, Cb, 0, wv, lane, 0);    // o12
  if (MAT) l2grow(X, tid, o12g, r);
  reduce_f16(X, lds2, S, S_O12, shard);

  bn_u_l<F32>(mr, og1, ob1, f, xn);
  chain1_to_lds<F32>(xn, ow1, X + tid*XSTR);              // a1
  mfma_layer<KIND_TANH  >(X, Wt, Cb, 1, wv, lane, 0);     // a2
  if (MAT) l2grow(X, tid, a2g, r);
  reduce_f16(X, lds2, S, S_A2, shard);
}
template<bool MAT>
__global__ __launch_bounds__(256) void k_pass2(const void* __restrict__ u,
    const void* pg1, const void* pb1, const void* pw1,
    const void* og1, const void* ob1, const void* ow1,
    const void* pg2, const void* pb2, const void* pw2,
    const void* og2, const void* ob2, const void* ow2,
    float* __restrict__ S, u16* o12g, u16* a2g){
  __shared__ u16 X[256*XSTR];
  __shared__ u16 Wt[2*32*XSTR];
  __shared__ float Cb[64];
  __shared__ float lds2[512];
  __shared__ float mr[8];
  __shared__ int sf;
  int isf = detect_u((const u16*)u, threadIdx.x, &sf);
  if (isf) pass2_body<true ,MAT>(u,pg1,pb1,pw1,og1,ob1,ow1,pg2,pb2,pw2,og2,ob2,ow2,S,o12g,a2g,X,Wt,Cb,lds2,mr);
  else     pass2_body<false,MAT>(u,pg1,pb1,pw1,og1,ob1,ow1,pg2,pb2,pw2,og2,ob2,ow2,S,o12g,a2g,X,Wt,Cb,lds2,mr);
}

// ---------------- pass3 (MAT): load o12g/a2g, L3 layers + softmax + pool + S_X ----------------
template<bool F32>
__device__ __forceinline__ void pass3m_body(const int* __restrict__ mask,
    const void* pg3, const void* pb3, const void* pw3,
    const void* og3, const void* ob3, const void* ow3,
    const u16* __restrict__ o12g, const u16* __restrict__ a2g,
    float* __restrict__ x, float* __restrict__ S,
    u16* X, u16* Wt, float* Cb, float* red2)
{
  int tid = threadIdx.x;
  int wv = tid >> 6, lane = tid & 63;
  int r = blockIdx.x*256 + tid;
  // L0 = 3O (stats S_A2), L1 = 3P (stats S_O12)
  fold2<F32>(S, S_A2, S_O12, og3,ob3,ow3, pg3,pb3,pw3, Wt, Cb, red2);

  u32 at_pk[16];
  int maskbase = blockIdx.x*256 + wv*64;

  g2lrow(a2g, r, X, tid);
  __syncthreads();
  mfma_logits_softmax(X, Wt, Cb, 0, wv, lane, mask, maskbase, at_pk);
  __syncthreads();
  g2lrow(o12g, r, X, tid);
  __syncthreads();
  mfma_layer<KIND_TANHRES_ATREG>(X, Wt, Cb, 1, wv, lane, at_pk); // xm*at

  __syncthreads();
  {
    int jj = tid & 31, cgrp = (tid >> 5) & 3, half = tid >> 7;
    float s2 = 0.f;
    for (int q2=0;q2<32;++q2) s2 += h2f(X[(half*128 + cgrp*32 + q2)*XSTR + jj]);
    red2[tid] = s2;
  }
  __syncthreads();
  if (tid < 64){
    int half = tid >> 5, j = tid & 31;
    float v = red2[half*128+j] + red2[half*128+32+j] + red2[half*128+64+j] + red2[half*128+96+j];
    x[(blockIdx.x*2 + half)*32 + j] = v;
    float* Sh = S + (blockIdx.x & (NSH-1))*SHARD;
    atomicAdd(&Sh[S_X+j], v);
    atomicAdd(&Sh[S_X+32+j], v*v);
  }
}
__global__ __launch_bounds__(256) void k_pass3m(const void* __restrict__ u, const int* __restrict__ mask,
    const void* pg3, const void* pb3, const void* pw3,
    const void* og3, const void* ob3, const void* ow3,
    const u16* o12g, const u16* a2g,
    float* __restrict__ x, float* __restrict__ S){
  __shared__ u16 X [256*XSTR];
  __shared__ u16 Wt[2*32*XSTR];
  __shared__ float Cb[64];
  __shared__ float red2[256];
  __shared__ int sf;
  int isf = detect_u((const u16*)u, threadIdx.x, &sf);
  if (isf) pass3m_body<true >(mask,pg3,pb3,pw3,og3,ob3,ow3,o12g,a2g,x,S,X,Wt,Cb,red2);
  else     pass3m_body<false>(mask,pg3,pb3,pw3,og3,ob3,ow3,o12g,a2g,x,S,X,Wt,Cb,red2);
}

// ---------------- pass3 (fallback, full recompute) ----------------
template<bool F32>
__device__ __forceinline__ void fold4(const float* __restrict__ S,
    int off0,int off1,int off2,int off3,
    const void* g0,const void* b0,const void* W0,
    const void* g1,const void* b1,const void* W1,
    const void* g2,const void* b2,const void* W2,
    const void* g3,const void* b3,const void* W3,
    u16* Wt, float* Cb, float* scr)
{
  int tid = threadIdx.x;
  __shared__ float scr2[256];
  if (tid < 128){
    int L = tid>>5, k = tid&31;
    const void* g = (L==0)?g0:(L==1)?g1:(L==2)?g2:g3;
    const void* b = (L==0)?b0:(L==1)?b1:(L==2)?b2:b3;
    int off = (L==0)?off0:(L==1)?off1:(L==2)?off2:off3;
    float s=0.f, q=0.f;
    for (int sh=0; sh<NSH; ++sh){
      s += S[sh*SHARD + off + k];
      q += S[sh*SHARD + off + 32 + k];
    }
    float m    = s*(1.0f/ROWS);
    float var  = q*(1.0f/ROWS) - m*m;
    float rstd = rsqrtf(var+EPS);
    float sc = rdp<F32>(g,k)*rstd;
    scr[tid]  = sc;
    scr2[tid] = rdp<F32>(b,k) - m*sc;
  }
  __syncthreads();
  if (tid < 128){
    int L = tid>>5, j = tid&31;
    const void* W = (L==0)?W0:(L==1)?W1:(L==2)?W2:W3;
    float c = 0.f;
#pragma unroll
    for (int k=0;k<32;++k){
      float Wv = rdp<F32>(W, j*32+k);
      Wt[(L*32+j)*XSTR + k] = f2h(Wv * scr[(L<<5)|k]);
      c += Wv * scr2[(L<<5)|k];
    }
    Cb[L*32+j] = c;
  }
  __syncthreads();
}

template<bool F32>
__device__ __forceinline__ void pass3_body(const void* __restrict__ u, const int* __restrict__ mask,
    const void* pg1, const void* pb1, const void* pw1,
    const void* og1, const void* ob1, const void* ow1,
    const void* pg2, const void* pb2, const void* pw2,
    const void* og2, const void* ob2, const void* ow2,
    const void* pg3, const void* pb3, const void* pw3,
    const void* og3, const void* ob3, const void* ow3,
    float* __restrict__ x, float* __restrict__ S,
    u16* X, u16* Wt, float* Cb, float* red2, float* mr)
{
  int tid = threadIdx.x;
  int wv = tid >> 6, lane = tid & 63;
  int r = blockIdx.x*256 + tid;
  prep_u(S, mr, tid);
  fold4<F32>(S, S_A1, S_A2, S_O1, S_O12,
             og2,ob2,ow2, og3,ob3,ow3, pg2,pb2,pw2, pg3,pb3,pw3,
             Wt, Cb, red2);

  float f[4], xn[4];
  load_u4<F32>(u,r,f);
  u32 at_pk[16];
  int maskbase = blockIdx.x*256 + wv*64;

  bn_u_l<F32>(mr, og1, ob1, f, xn);
  chain1_to_lds<F32>(xn, ow1, X + tid*XSTR);
  mfma_layer<KIND_TANH>(X, Wt, Cb, 0, wv, lane, 0);
  mfma_logits_softmax(X, Wt, Cb, 1, wv, lane, mask, maskbase, at_pk);

  bn_u_l<F32>(mr, pg1, pb1, f, xn);
  chain1_to_lds<F32>(xn, pw1, X + tid*XSTR);
  mfma_layer<KIND_TANHRES   >(X, Wt, Cb, 2, wv, lane, 0);
  mfma_layer<KIND_TANHRES_ATREG>(X, Wt, Cb, 3, wv, lane, at_pk);

  __syncthreads();
  {
    int jj = tid & 31, cgrp = (tid >> 5) & 3, half = tid >> 7;
    float s2 = 0.f;
    for (int q2=0;q2<32;++q2) s2 += h2f(X[(half*128 + cgrp*32 + q2)*XSTR + jj]);
    red2[tid] = s2;
  }
  __syncthreads();
  if (tid < 64){
    int half = tid >> 5, j = tid & 31;
    float v = red2[half*128+j] + red2[half*128+32+j] + red2[half*128+64+j] + red2[half*128+96+j];
    x[(blockIdx.x*2 + half)*32 + j] = v;
    float* Sh = S + (blockIdx.x & (NSH-1))*SHARD;
    atomicAdd(&Sh[S_X+j], v);
    atomicAdd(&Sh[S_X+32+j], v*v);
  }
}
__global__ __launch_bounds__(256) void k_pass3(const void* __restrict__ u, const int* __restrict__ mask,
    const void* pg1, const void* pb1, const void* pw1,
    const void* og1, const void* ob1, const void* ow1,
    const void* pg2, const void* pb2, const void* pw2,
    const void* og2, const void* ob2, const void* ow2,
    const void* pg3, const void* pb3, const void* pw3,
    const void* og3, const void* ob3, const void* ow3,
    float* __restrict__ x, float* __restrict__ S){
  __shared__ u16 X [256*XSTR];
  __shared__ u16 Wt[4*32*XSTR];
  __shared__ float Cb[128];
  __shared__ float red2[256];
  __shared__ float mr[8];
  __shared__ int sf;
  int isf = detect_u((const u16*)u, threadIdx.x, &sf);
  if (isf) pass3_body<true >(u,mask,pg1,pb1,pw1,og1,ob1,ow1,pg2,pb2,pw2,og2,ob2,ow2,
                             pg3,pb3,pw3,og3,ob3,ow3,x,S,X,Wt,Cb,red2,mr);
  else     pass3_body<false>(u,mask,pg1,pb1,pw1,og1,ob1,ow1,pg2,pb2,pw2,og2,ob2,ow2,
                             pg3,pb3,pw3,og3,ob3,ow3,x,S,X,Wt,Cb,red2,mr);
}

// ---------------- fused theta chain: 16 blocks, spin-barrier grid sync ----------------
// Row data stays in registers across layers; only stats cross blocks (shard = blockIdx).
template<bool F32>
__device__ __forceinline__ void theta_all_body(const float* __restrict__ x,
    float* __restrict__ S, u32* __restrict__ bars,
    const void* tg1, const void* tb1, const void* tw1,
    const void* tg2, const void* tb2, const void* tw2,
    const void* tg3, const void* tb3, const void* tw3,
    const void* tg4, const void* tb4, const void* tw4, const void* tbb4,
    void* out, float* lds, float* lds2)
{
  int tid = threadIdx.x;
  int blk = blockIdx.x;              // 16 blocks x 256 threads = 4096 rows
  int r = blk*256 + tid;
  float v[32];
#pragma unroll
  for (int k=0;k<32;++k) v[k] = x[(size_t)r*32+k];

  const void* gs[3]  = {tg1, tg2, tg3};
  const void* bs[3]  = {tb1, tb2, tb3};
  const void* Ws[3]  = {tw1, tw2, tw3};
  const int offin[4]  = {S_X, S_X1, S_X2, S_X3};
  const int offout[3] = {S_X1, S_X2, S_X3};

#pragma unroll
  for (int L=0; L<3; ++L){
    int nsh = (L==0) ? NSH : 16;     // S_X from 2048 blocks (64 shards); later layers 16 shards
    if (tid < 32){
      float s=0.f, q=0.f;
      for (int sh=0; sh<nsh; ++sh){
        s += S[sh*SHARD + offin[L] + tid];
        q += S[sh*SHARD + offin[L] + 32 + tid];
      }
      float m = s*(1.0f/BROWS);
      float var = q*(1.0f/BROWS) - m*m;
      lds2[tid]    = m;
      lds2[32+tid] = rsqrtf(var + EPS);
    }
    __syncthreads();
    float* Xp = lds + tid*33;
#pragma unroll
    for (int k=0;k<32;++k)
      Xp[k] = (v[k] - lds2[k]) * (rdp<F32>(gs[L],k)*lds2[32+k]) + rdp<F32>(bs[L],k);
    __syncthreads();
#pragma unroll
    for (int j=0;j<32;++j){
      float acc = 0.f;
#pragma unroll
      for (int k=0;k<32;++k) acc = fmaf(rdp<F32>(Ws[L], j*32+k), Xp[k], acc);
      v[j] = tanh_fast(acc);
    }
    __syncthreads();
#pragma unroll
    for (int j=0;j<32;++j) Xp[j] = v[j];
    reduce_f32(lds, lds2, S, offout[L], blk);    // shard = blk: zero contention
    gbar(&bars[L], tid, 16);
  }

  // final layer: bn + dot(w4) + b4
  if (tid < 32){
    float s=0.f, q=0.f;
    for (int sh=0; sh<16; ++sh){
      s += S[sh*SHARD + S_X3 + tid];
      q += S[sh*SHARD + S_X3 + 32 + tid];
    }
    float m = s*(1.0f/BROWS);
    float var = q*(1.0f/BROWS) - m*m;
    lds2[tid]    = m;
    lds2[32+tid] = rsqrtf(var + EPS);
  }
  __syncthreads();
  float acc = rdp<F32>(tbb4, 0);
#pragma unroll
  for (int k=0;k<32;++k){
    float xnv = (v[k] - lds2[k]) * (rdp<F32>(tg4,k)*lds2[32+k]) + rdp<F32>(tb4,k);
    acc = fmaf(rdp<F32>(tw4,k), xnv, acc);
  }
  if (F32) ((float*)out)[r] = acc;
  else     ((u16*)out)[r]  = f2b(acc);
}
__global__ __launch_bounds__(256) void k_theta_all(const void* __restrict__ u,
    const float* __restrict__ x, float* __restrict__ S, u32* __restrict__ bars,
    const void* tg1, const void* tb1, const void* tw1,
    const void* tg2, const void* tb2, const void* tw2,
    const void* tg3, const void* tb3, const void* tw3,
    const void* tg4, const void* tb4, const void* tw4, const void* tbb4,
    void* out){
  __shared__ float lds[256*33];
  __shared__ float lds2[512];
  __shared__ int sf;
  int isf = detect_u((const u16*)u, threadIdx.x, &sf);
  if (isf) theta_all_body<true >(x,S,bars,tg1,tb1,tw1,tg2,tb2,tw2,tg3,tb3,tw3,tg4,tb4,tw4,tbb4,out,lds,lds2);
  else     theta_all_body<false>(x,S,bars,tg1,tb1,tw1,tg2,tb2,tw2,tg3,tb3,tw3,tg4,tb4,tw4,tbb4,out,lds,lds2);
}

extern "C" void kernel_launch(void* const* d_in, const int* in_sizes, int n_in,
                              void* d_out, int out_size, void* d_ws, size_t ws_size,
                              hipStream_t stream)
{
  const void* u    = d_in[0];
  const int*  mask = (const int*)d_in[1];
  const void *pg1=d_in[2],  *pb1=d_in[3],  *pw1=d_in[4];
  const void *pg2=d_in[5],  *pb2=d_in[6],  *pw2=d_in[7];
  const void *pg3=d_in[8],  *pb3=d_in[9],  *pw3=d_in[10];
  const void *og1=d_in[11], *ob1=d_in[12], *ow1=d_in[13];
  const void *og2=d_in[14], *ob2=d_in[15], *ow2=d_in[16];
  const void *og3=d_in[17], *ob3=d_in[18], *ow3=d_in[19];
  const void *tg1=d_in[20], *tb1=d_in[21], *tw1=d_in[22];
  const void *tg2=d_in[23], *tb2=d_in[24], *tw2=d_in[25];
  const void *tg3=d_in[26], *tb3=d_in[27], *tw3=d_in[28];
  const void *tg4=d_in[29], *tb4=d_in[30], *tw4=d_in[31], *tbb4=d_in[32];

  char* ws = (char*)d_ws;
  u32*   bars = (u32*)(ws + 256);            // 3 phase counters (zeroed below)
  float* S    = (float*)(ws + 4096);         // 64 shards x 1024 floats = 256 KB
  float* x    = (float*)(ws + 524288);       // 4096*32 f32

  const size_t MB = 1024*1024;
  u16* o12g = (u16*)(ws + 8*MB);             // 32 MB each
  u16* a2g  = (u16*)(ws + 40*MB);
  bool MAT = ws_size >= 73*MB;               // constant per process -> graph-safe

  (void)hipMemsetAsync(ws, 0, 4096 + NSH*SHARD*4, stream);  // zero bars + sharded stats
  k_stats_u<<<1024, 256, 0, stream>>>(u, S);
  k_pass1<<<2048, 256, 0, stream>>>(u, pg1,pb1,pw1, og1,ob1,ow1, S);
  if (MAT){
    k_pass2<true ><<<2048, 256, 0, stream>>>(u, pg1,pb1,pw1, og1,ob1,ow1,
                                             pg2,pb2,pw2, og2,ob2,ow2, S, o12g, a2g);
    k_pass3m<<<2048, 256, 0, stream>>>(u, mask, pg3,pb3,pw3, og3,ob3,ow3, o12g, a2g, x, S);
  } else {
    k_pass2<false><<<2048, 256, 0, stream>>>(u, pg1,pb1,pw1, og1,ob1,ow1,
                                             pg2,pb2,pw2, og2,ob2,ow2, S, o12g, a2g);
    k_pass3<<<2048, 256, 0, stream>>>(u, mask, pg1,pb1,pw1, og1,ob1,ow1,
                                      pg2,pb2,pw2, og2,ob2,ow2,
                                      pg3,pb3,pw3, og3,ob3,ow3, x, S);
  }
  k_theta_all<<<16, 256, 0, stream>>>(u, x, S, bars,
                                      tg1,tb1,tw1, tg2,tb2,tw2, tg3,tb3,tw3,
                                      tg4,tb4,tw4,tbb4, d_out);
}